// Round 8
// baseline (9789.328 us; speedup 1.0000x reference)
//
#include <hip/hip_runtime.h>
#include <hip/hip_bf16.h>

// ---------------- problem constants ----------------
// B=32, S=512, D=512, K=2048, NHEADS=8, NHASH=4, HLEN=16; N = B*S = 16384.
// d_out is FLOAT32. Intermediates f32-stored, f64-accumulated.
// VQ argmin emulates the reference's f32 dist combine (absorption quantization)
// with np.argmin first-index tie-break.

#define GF_BIAS 1
#define GF_RELU 2
#define GF_ADD  4
#define GF_POS  8
#define GF_ACC  16

// output layout (f32 elements), return order — total 43,008,001
static constexpr long long O_QUANT = 0LL;        // 8388608
static constexpr long long O_LOSS  = 8388608LL;  // 1
static constexpr long long O_IDX   = 8388609LL;  // 16384
static constexpr long long O_HASH  = 8404993LL;  // 1048576
static constexpr long long O_REG   = 9453569LL;  // 33554432
static constexpr long long O_END   = 43008001LL;

// workspace layout (f32 element offsets) — total 34,271,232 f32 = 130.7 MiB
static constexpr long long W_XP    = 0LL;
static constexpr long long W_CT    = 8388608LL;
static constexpr long long W_PROJ  = 16777216LL;
static constexpr long long W_VW    = 25165824LL;
static constexpr long long W_HREG  = 33554432LL;
static constexpr long long W_T     = 34078720LL;
static constexpr long long W_IDX   = 34209792LL;
static constexpr long long W_ASUM  = 34226176LL;
static constexpr long long W_CBB   = 34258944LL;
static constexpr long long W_LPART = 34263040LL;
static constexpr long long W_END   = 34271232LL;

// ---------------- generic GEMM, f32 storage / f64 accumulate ------------------
template<int FLAGS>
__global__ __launch_bounds__(256)
void gemm_bt_r8(const float* __restrict__ A, const float* __restrict__ Bm,
                const float* __restrict__ bias, const float* __restrict__ pos,
                const float* __restrict__ addsrc, float* __restrict__ C,
                int Kdim, int lda, int ldb, int ldc)
{
    __shared__ float As[16][68];
    __shared__ float Bs[16][68];
    const int tid = threadIdx.x;
    const int tx = tid & 15, ty = tid >> 4;
    const int bm = blockIdx.x * 64, bn = blockIdx.y * 64;
    const int lr = tid >> 2;          // 0..63
    const int lk = (tid & 3) << 2;    // 0,4,8,12
    const float* Arow = A  + (long long)(bm + lr) * lda + lk;
    const float* Brow = Bm + (long long)(bn + lr) * ldb + lk;
    double acc[4][4] = {};
    for (int k0 = 0; k0 < Kdim; k0 += 16) {
        float4 av = *(const float4*)(Arow + k0);
        float4 bv = *(const float4*)(Brow + k0);
        __syncthreads();
        As[lk+0][lr]=av.x; As[lk+1][lr]=av.y; As[lk+2][lr]=av.z; As[lk+3][lr]=av.w;
        Bs[lk+0][lr]=bv.x; Bs[lk+1][lr]=bv.y; Bs[lk+2][lr]=bv.z; Bs[lk+3][lr]=bv.w;
        __syncthreads();
        #pragma unroll
        for (int kk = 0; kk < 16; ++kk) {
            double a[4], b[4];
            #pragma unroll
            for (int i=0;i<4;i++) a[i] = (double)As[kk][ty*4+i];
            #pragma unroll
            for (int j=0;j<4;j++) b[j] = (double)Bs[kk][tx*4+j];
            #pragma unroll
            for (int i=0;i<4;i++)
                #pragma unroll
                for (int j=0;j<4;j++)
                    acc[i][j] = fma(a[i], b[j], acc[i][j]);
        }
    }
    #pragma unroll
    for (int i=0;i<4;i++){
        const int row = bm + ty*4 + i;
        #pragma unroll
        for (int j=0;j<4;j++){
            const int col = bn + tx*4 + j;
            double v = acc[i][j];
            if constexpr (FLAGS & GF_BIAS) v += (double)bias[col];
            if constexpr (FLAGS & GF_POS)  v += (double)pos[(long long)(row & 511)*512 + col];
            if constexpr (FLAGS & GF_ADD)  v += (double)addsrc[(long long)row*ldc + col];
            if constexpr (FLAGS & GF_ACC)  v += (double)C[(long long)row*ldc + col];
            if constexpr (FLAGS & GF_RELU) v = (v > 0.0) ? v : 0.0;
            C[(long long)row*ldc + col] = (float)v;
        }
    }
}

// ---------------- conv1d (same pad) as implicit GEMM, f64 accumulate ---------
template<int KT>
__global__ __launch_bounds__(256)
void conv_relu_r8(const float* __restrict__ xp, const float* __restrict__ wt,
                  const float* __restrict__ bias, float* __restrict__ outp)
{
    constexpr int PAD = KT / 2;
    constexpr int KD  = KT * 512;
    __shared__ float As[16][68];
    __shared__ float Bs[16][68];
    const int tid = threadIdx.x;
    const int tx = tid & 15, ty = tid >> 4;
    const int bm = blockIdx.x * 64, bn = blockIdx.y * 64;
    const int lr = tid >> 2;
    const int lk = (tid & 3) << 2;
    const int n = bm + lr;
    const int s = n & 511;
    const float* Brow = wt + (long long)(bn + lr) * KD + lk;
    double acc[4][4] = {};
    for (int k0 = 0; k0 < KD; k0 += 16) {
        const int t  = k0 >> 9;
        const int i0 = (k0 & 511) + lk;
        const int sp = s + t - PAD;
        float4 av = make_float4(0.f,0.f,0.f,0.f);
        if (sp >= 0 && sp < 512)
            av = *(const float4*)(xp + (long long)(n + t - PAD)*512 + i0);
        float4 bv = *(const float4*)(Brow + k0);
        __syncthreads();
        As[lk+0][lr]=av.x; As[lk+1][lr]=av.y; As[lk+2][lr]=av.z; As[lk+3][lr]=av.w;
        Bs[lk+0][lr]=bv.x; Bs[lk+1][lr]=bv.y; Bs[lk+2][lr]=bv.z; Bs[lk+3][lr]=bv.w;
        __syncthreads();
        #pragma unroll
        for (int kk = 0; kk < 16; ++kk) {
            double a[4], b[4];
            #pragma unroll
            for (int i=0;i<4;i++) a[i] = (double)As[kk][ty*4+i];
            #pragma unroll
            for (int j=0;j<4;j++) b[j] = (double)Bs[kk][tx*4+j];
            #pragma unroll
            for (int i=0;i<4;i++)
                #pragma unroll
                for (int j=0;j<4;j++)
                    acc[i][j] = fma(a[i], b[j], acc[i][j]);
        }
    }
    #pragma unroll
    for (int i=0;i<4;i++){
        const int row = bm + ty*4 + i;
        #pragma unroll
        for (int j=0;j<4;j++){
            const int col = bn + tx*4 + j;
            double v = acc[i][j] + (double)bias[col];
            outp[(long long)row*512 + col] = (float)((v > 0.0) ? v : 0.0);
        }
    }
}

// conv weight transpose: w[o][i][t] -> wt[o][t][i]
template<int KT>
__global__ __launch_bounds__(256)
void conv_w_tr_r8(const float* __restrict__ w, float* __restrict__ wt)
{
    long long i = (long long)blockIdx.x*256 + threadIdx.x;
    int o  = (int)(i / (512*KT));
    int rem= (int)(i % (512*KT));
    int t  = rem >> 9;
    int ii = rem & 511;
    wt[i] = w[(long long)o*512*KT + (long long)ii*KT + t];
}

// ---------------- fused attention (f32 storage, f64 math) --------------------
__global__ __launch_bounds__(256)
void attn_fused_r8(const float* __restrict__ proj, const float* __restrict__ inw,
                   const float* __restrict__ inb, const float* __restrict__ Kbuf,
                   const float* __restrict__ Vbuf, float* __restrict__ att)
{
    __shared__ float Qs[64][65];
    __shared__ float Kt[64][65];   // K tile, then P tile
    __shared__ float Vt[64][65];
    const int tid = threadIdx.x;
    const int tx = tid & 15, ty = tid >> 4;
    const int bid = blockIdx.x;
    const int qt = bid & 7, h = (bid >> 3) & 7, b = bid >> 6;
    const int row0 = b*512 + qt*64;
    const int lr = tid >> 2, lk = (tid & 3) << 2;

    { // Q = (proj @ Wq^T + bq) * 0.125, f64 accumulate
        double qa[4][4] = {};
        const float* Arow = proj + (long long)(row0 + lr)*512 + lk;
        const float* Brow = inw  + (long long)(h*64 + lr)*512 + lk;
        for (int k0 = 0; k0 < 512; k0 += 16) {
            float4 av = *(const float4*)(Arow + k0);
            float4 bv = *(const float4*)(Brow + k0);
            __syncthreads();
            Kt[lk+0][lr]=av.x; Kt[lk+1][lr]=av.y; Kt[lk+2][lr]=av.z; Kt[lk+3][lr]=av.w;
            Vt[lk+0][lr]=bv.x; Vt[lk+1][lr]=bv.y; Vt[lk+2][lr]=bv.z; Vt[lk+3][lr]=bv.w;
            __syncthreads();
            #pragma unroll
            for (int kk = 0; kk < 16; ++kk) {
                double a[4], bb[4];
                #pragma unroll
                for (int i=0;i<4;i++) a[i] = (double)Kt[kk][ty*4+i];
                #pragma unroll
                for (int j=0;j<4;j++) bb[j] = (double)Vt[kk][tx*4+j];
                #pragma unroll
                for (int i=0;i<4;i++)
                    #pragma unroll
                    for (int j=0;j<4;j++)
                        qa[i][j] = fma(a[i], bb[j], qa[i][j]);
            }
        }
        __syncthreads();
        #pragma unroll
        for (int i=0;i<4;i++)
            #pragma unroll
            for (int j=0;j<4;j++)
                Qs[ty*4+i][tx*4+j] = (float)((qa[i][j] + (double)inb[h*64 + tx*4+j]) * 0.125);
    }

    double m[4], l[4], acc[4][4] = {};
    #pragma unroll
    for (int i=0;i<4;i++){ m[i] = -1e300; l[i] = 0.0; }

    for (int kv = 0; kv < 512; kv += 64) {
        __syncthreads();
        #pragma unroll
        for (int u = 0; u < 16; ++u) {
            int e = u*256 + tid;
            int r = e >> 6, c = e & 63;
            Kt[r][c] = Kbuf[(long long)(b*512 + kv + r)*512 + h*64 + c];
            Vt[r][c] = Vbuf[(long long)(b*512 + kv + r)*512 + h*64 + c];
        }
        __syncthreads();
        double sc[4][4] = {};
        for (int d = 0; d < 64; ++d) {
            double a[4], bb[4];
            #pragma unroll
            for (int i=0;i<4;i++) a[i] = (double)Qs[ty*4+i][d];
            #pragma unroll
            for (int j=0;j<4;j++) bb[j] = (double)Kt[tx*4+j][d];
            #pragma unroll
            for (int i=0;i<4;i++)
                #pragma unroll
                for (int j=0;j<4;j++)
                    sc[i][j] = fma(a[i], bb[j], sc[i][j]);
        }
        #pragma unroll
        for (int i=0;i<4;i++){
            double tm = fmax(fmax(sc[i][0],sc[i][1]), fmax(sc[i][2],sc[i][3]));
            #pragma unroll
            for (int msk=1; msk<16; msk<<=1) tm = fmax(tm, __shfl_xor(tm, msk, 64));
            double mn = fmax(m[i], tm);
            double scale = exp(m[i] - mn);
            double rs = 0.0;
            #pragma unroll
            for (int j=0;j<4;j++){ double p = exp(sc[i][j]-mn); sc[i][j]=p; rs += p; }
            #pragma unroll
            for (int msk=1; msk<16; msk<<=1) rs += __shfl_xor(rs, msk, 64);
            l[i] = l[i]*scale + rs;
            m[i] = mn;
            #pragma unroll
            for (int j=0;j<4;j++) acc[i][j] *= scale;
        }
        __syncthreads();   // all sc reads of Kt done; reuse Kt as P tile (f32)
        #pragma unroll
        for (int i=0;i<4;i++)
            #pragma unroll
            for (int j=0;j<4;j++)
                Kt[ty*4+i][tx*4+j] = (float)sc[i][j];
        __syncthreads();
        for (int d = 0; d < 64; ++d) {
            double p[4], v[4];
            #pragma unroll
            for (int i=0;i<4;i++) p[i] = (double)Kt[ty*4+i][d];
            #pragma unroll
            for (int j=0;j<4;j++) v[j] = (double)Vt[d][tx*4+j];
            #pragma unroll
            for (int i=0;i<4;i++)
                #pragma unroll
                for (int j=0;j<4;j++)
                    acc[i][j] = fma(p[i], v[j], acc[i][j]);
        }
    }
    #pragma unroll
    for (int i=0;i<4;i++)
        #pragma unroll
        for (int j=0;j<4;j++)
            att[(long long)(row0 + ty*4+i)*512 + h*64 + tx*4+j] = (float)(acc[i][j] / l[i]);
}

// ---------------- row sum of squares (f64), 512-col rows ---------------------
__global__ __launch_bounds__(256)
void row_sumsq_r8(const float* __restrict__ X, double* __restrict__ outp)
{
    const int row  = blockIdx.x*4 + (threadIdx.x >> 6);
    const int lane = threadIdx.x & 63;
    double s = 0.0;
    #pragma unroll
    for (int u = 0; u < 8; ++u) {
        float v = X[(long long)row*512 + lane + u*64];
        s += (double)v * (double)v;
    }
    #pragma unroll
    for (int msk = 32; msk; msk >>= 1) s += __shfl_xor(s, msk, 64);
    if (lane == 0) outp[row] = s;
}

// ---------------- VQ argmin: f64 dot, f32-ABSORBED dist compare --------------
// Emulates the reference's f32 combine: qd = fl32(fl32(A+B) - fl32(2*dot)),
// argmin in f32 with first-index tie-break (np.argmin semantics). Sub-quantum
// gaps become exact f32 ties resolved by lower index — matching both refs.
__global__ __launch_bounds__(256)
void vq_argmin_r8(const float* __restrict__ enc, const float* __restrict__ cb,
                  const double* __restrict__ Asum, const double* __restrict__ cbB,
                  int* __restrict__ idxout)
{
    __shared__ float Es[16][68];
    __shared__ float Cs[16][68];
    __shared__ float bv_s[64][17];
    __shared__ int   bi_s[64][17];
    const int tid = threadIdx.x;
    const int tx = tid & 15, ty = tid >> 4;
    const int lr = tid >> 2, lk = (tid & 3) << 2;
    const int bm = blockIdx.x * 64;
    float bestv[4]; int besti[4];
    #pragma unroll
    for (int i=0;i<4;i++){ bestv[i] = 3.0e38f; besti[i] = 2048; }

    for (int ct = 0; ct < 2048; ct += 64) {
        double macc[4][4] = {};
        for (int k0 = 0; k0 < 512; k0 += 16) {
            float4 av = *(const float4*)(enc + (long long)(bm + lr)*512 + k0 + lk);
            float4 bv = *(const float4*)(cb  + (long long)(ct + lr)*512 + k0 + lk);
            __syncthreads();
            Es[lk+0][lr]=av.x; Es[lk+1][lr]=av.y; Es[lk+2][lr]=av.z; Es[lk+3][lr]=av.w;
            Cs[lk+0][lr]=bv.x; Cs[lk+1][lr]=bv.y; Cs[lk+2][lr]=bv.z; Cs[lk+3][lr]=bv.w;
            __syncthreads();
            #pragma unroll
            for (int kk = 0; kk < 16; ++kk) {
                double a[4], b[4];
                #pragma unroll
                for (int i=0;i<4;i++) a[i] = (double)Es[kk][ty*4+i];
                #pragma unroll
                for (int j=0;j<4;j++) b[j] = (double)Cs[kk][tx*4+j];
                #pragma unroll
                for (int i=0;i<4;i++)
                    #pragma unroll
                    for (int j=0;j<4;j++)
                        macc[i][j] = fma(a[i], b[j], macc[i][j]);
            }
        }
        #pragma unroll
        for (int i=0;i<4;i++){
            const float anf = (float)Asum[bm + ty*4 + i];
            #pragma unroll
            for (int j=0;j<4;j++){
                const int ci = ct + tx*4 + j;
                const float bf  = (float)cbB[ci];
                const float s1  = anf + bf;                 // fl32(A+B)
                const float df  = (float)(2.0 * macc[i][j]); // fl32(2*dot)
                const float qd  = s1 - df;                   // fl32 combine
                if (qd < bestv[i] || (qd == bestv[i] && ci < besti[i])) {
                    bestv[i] = qd; besti[i] = ci;
                }
            }
        }
    }
    #pragma unroll
    for (int i=0;i<4;i++){ bv_s[ty*4+i][tx] = bestv[i]; bi_s[ty*4+i][tx] = besti[i]; }
    __syncthreads();
    if (tid < 64) {
        float bv = bv_s[tid][0]; int bi = bi_s[tid][0];
        #pragma unroll
        for (int x = 1; x < 16; ++x) {
            float v = bv_s[tid][x]; int ii = bi_s[tid][x];
            if (v < bv || (v == bv && ii < bi)) { bv = v; bi = ii; }
        }
        idxout[bm + tid] = bi & 2047;
    }
}

// ---------------- vq loss: two-stage, atomic-free ----------------------------
__global__ __launch_bounds__(256)
void vq_loss_partial_r8(const float* __restrict__ enc, const float* __restrict__ cb,
                        const int* __restrict__ idxp, double* __restrict__ part)
{
    __shared__ double red[4];
    const int row  = blockIdx.x*4 + (threadIdx.x >> 6);
    const int lane = threadIdx.x & 63;
    const int ci = idxp[row] & 2047;
    double s = 0.0;
    #pragma unroll
    for (int u = 0; u < 8; ++u) {
        int d = lane + u*64;
        double dv = (double)cb[(long long)ci*512 + d] - (double)enc[(long long)row*512 + d];
        s += dv * dv;
    }
    #pragma unroll
    for (int msk = 32; msk; msk >>= 1) s += __shfl_xor(s, msk, 64);
    if (lane == 0) red[threadIdx.x >> 6] = s;
    __syncthreads();
    if (threadIdx.x == 0)
        part[blockIdx.x] = red[0] + red[1] + red[2] + red[3];
}

// ---------------- regime softmax rows (in place) -----------------------------
__global__ __launch_bounds__(256)
void softmax_rows_r8(float* __restrict__ R)
{
    const int row = blockIdx.x;
    const int tid = threadIdx.x;
    __shared__ float  redf[256];
    __shared__ double redd[256];
    float* p = R + (long long)row * 2048;
    float mx = -1e30f;
    for (int c = tid; c < 2048; c += 256) mx = fmaxf(mx, p[c]);
    redf[tid] = mx; __syncthreads();
    for (int s2 = 128; s2; s2 >>= 1) { if (tid < s2) redf[tid] = fmaxf(redf[tid], redf[tid+s2]); __syncthreads(); }
    mx = redf[0];
    double sum = 0.0;
    for (int c = tid; c < 2048; c += 256) { float e = expf(p[c] - mx); p[c] = e; sum += e; }
    redd[tid] = sum; __syncthreads();
    for (int s2 = 128; s2; s2 >>= 1) { if (tid < s2) redd[tid] += redd[tid+s2]; __syncthreads(); }
    double tot = redd[0];
    for (int c = tid; c < 2048; c += 256) p[c] = (float)((double)p[c] / tot);
}

// ---------------- hash table per codebook entry ------------------------------
__global__ __launch_bounds__(256)
void hash_table_r8(const float* __restrict__ cb, const float* __restrict__ hw,
                   float* __restrict__ T)
{
    const int k = blockIdx.x*4 + (threadIdx.x >> 6);
    const int j = threadIdx.x & 63;
    double s = 0.0;
    for (int d = 0; d < 512; ++d)
        s += (double)cb[(long long)k*512 + d] * (double)hw[(long long)j*512 + d];
    T[(long long)k*64 + j] = (s > 0.0) ? 1.0f : 0.0f;
}

// ---------------- output writers (f32 d_out) ---------------------------------
__global__ void write_loss_r8(const double* __restrict__ part,
                              float* __restrict__ out)
{
    __shared__ double red[256];
    double s = 0.0;
    for (int i = threadIdx.x; i < 4096; i += 256) s += part[i];
    red[threadIdx.x] = s; __syncthreads();
    for (int s2 = 128; s2; s2 >>= 1) {
        if (threadIdx.x < s2) red[threadIdx.x] += red[threadIdx.x + s2];
        __syncthreads();
    }
    if (threadIdx.x == 0)
        out[O_LOSS] = (float)(1.25 * red[0] / 8388608.0);
}

__global__ __launch_bounds__(256)
void write_regime_r8(const float* __restrict__ R, const int* __restrict__ idxp,
                     float* __restrict__ out)
{
    long long i = (long long)blockIdx.x*256 + threadIdx.x;
    if (i >= 33554432LL) return;
    int n = (int)(i >> 11), c = (int)(i & 2047);
    int ci = idxp[n] & 2047;
    out[O_REG + i] = R[(long long)ci*2048 + c];
}

__global__ __launch_bounds__(256)
void write_hash_r8(const float* __restrict__ T, const int* __restrict__ idxp,
                   float* __restrict__ out)
{
    long long i = (long long)blockIdx.x*256 + threadIdx.x;
    if (i >= 1048576LL) return;
    int n = (int)(i >> 6), j = (int)(i & 63);
    int ci = idxp[n] & 2047;
    out[O_HASH + i] = T[(long long)ci*64 + j];
}

__global__ __launch_bounds__(256)
void write_idx_r8(const int* __restrict__ idxp, float* __restrict__ out)
{
    int n = blockIdx.x*256 + threadIdx.x;
    if (n >= 16384) return;
    out[O_IDX + n] = (float)(idxp[n] & 2047);
}

__global__ __launch_bounds__(256)
void write_quant_r8(const float* __restrict__ cb, const int* __restrict__ idxp,
                    float* __restrict__ out)
{
    long long i = (long long)blockIdx.x*256 + threadIdx.x;
    if (i >= 8388608LL) return;
    int n = (int)(i >> 9), d = (int)(i & 511);
    int ci = idxp[n] & 2047;
    out[O_QUANT + i] = cb[(long long)ci*512 + d];
}

// ---------------- launcher ----------------------------------------------------
extern "C" void kernel_launch(void* const* d_in, const int* in_sizes, int n_in,
                              void* d_out, int out_size, void* d_ws, size_t ws_size,
                              hipStream_t stream)
{
    (void)in_sizes; (void)n_in; (void)out_size;
    const float* market = (const float*)d_in[0];
    const float* W_in   = (const float*)d_in[1];
    const float* b_in   = (const float*)d_in[2];
    const float* pos    = (const float*)d_in[3];
    const float* c3w = (const float*)d_in[4];  const float* c3b = (const float*)d_in[5];
    const float* c5w = (const float*)d_in[6];  const float* c5b = (const float*)d_in[7];
    const float* c7w = (const float*)d_in[8];  const float* c7b = (const float*)d_in[9];
    const float* c9w = (const float*)d_in[10]; const float* c9b = (const float*)d_in[11];
    const float* msw = (const float*)d_in[12]; const float* msb = (const float*)d_in[13];
    const float* inw = (const float*)d_in[14]; const float* inb = (const float*)d_in[15];
    const float* aow = (const float*)d_in[16]; const float* aob = (const float*)d_in[17];
    const float* cb  = (const float*)d_in[18]; const float* hw  = (const float*)d_in[19];
    const float* r1w = (const float*)d_in[20]; const float* r1b = (const float*)d_in[21];
    const float* r2w = (const float*)d_in[22]; const float* r2b = (const float*)d_in[23];

    if (ws_size < (size_t)W_END * sizeof(float)) return; // insufficient scratch

    float* ws    = (float*)d_ws;
    float* xp    = ws + W_XP;
    float* convt = ws + W_CT;
    float* projp = ws + W_PROJ;
    float* wt3   = ws + W_VW;        // conv weights time-share the V region
    float* wt5   = wt3 + 512*512*3;
    float* wt7   = wt5 + 512*512*5;
    float* wt9   = wt7 + 512*512*7;
    float* Vbufp = ws + W_VW;
    float* hregp = ws + W_HREG;
    float* Tp    = ws + W_T;
    int*    idxp  = (int*)(ws + W_IDX);
    double* asump = (double*)(ws + W_ASUM);
    double* cbbp  = (double*)(ws + W_CBB);
    double* lpart = (double*)(ws + W_LPART);

    float* out = (float*)d_out;   // f32 output buffer

    float* attp  = xp;      // xp dead after conv9
    float* Kbufp = convt;   // conv_tmp dead after last ms gemm
    float* encp  = convt;   // K dead after attn
    float* Rp    = projp;   // proj dead after enc gemm

    // conv weight transposes
    conv_w_tr_r8<3><<<3072, 256, 0, stream>>>(c3w, wt3);
    conv_w_tr_r8<5><<<5120, 256, 0, stream>>>(c5w, wt5);
    conv_w_tr_r8<7><<<7168, 256, 0, stream>>>(c7w, wt7);
    conv_w_tr_r8<9><<<9216, 256, 0, stream>>>(c9w, wt9);

    const dim3 gN512(256, 8);

    // xp = market @ W_in^T + b_in + pos_enc
    gemm_bt_r8<GF_BIAS|GF_POS><<<gN512, 256, 0, stream>>>(market, W_in, b_in, pos, nullptr, xp, 512, 512, 512, 512);

    // proj = sum_c relu(conv_c(xp)) @ msW_c^T (+ bias on first)
    conv_relu_r8<3><<<gN512, 256, 0, stream>>>(xp, wt3, c3b, convt);
    gemm_bt_r8<GF_BIAS><<<gN512, 256, 0, stream>>>(convt, msw + 0*512, msb, nullptr, nullptr, projp, 512, 512, 2048, 512);
    conv_relu_r8<5><<<gN512, 256, 0, stream>>>(xp, wt5, c5b, convt);
    gemm_bt_r8<GF_ACC><<<gN512, 256, 0, stream>>>(convt, msw + 1*512, nullptr, nullptr, nullptr, projp, 512, 512, 2048, 512);
    conv_relu_r8<7><<<gN512, 256, 0, stream>>>(xp, wt7, c7b, convt);
    gemm_bt_r8<GF_ACC><<<gN512, 256, 0, stream>>>(convt, msw + 2*512, nullptr, nullptr, nullptr, projp, 512, 512, 2048, 512);
    conv_relu_r8<9><<<gN512, 256, 0, stream>>>(xp, wt9, c9b, convt);
    gemm_bt_r8<GF_ACC><<<gN512, 256, 0, stream>>>(convt, msw + 3*512, nullptr, nullptr, nullptr, projp, 512, 512, 2048, 512);

    // K, V projections (Q fused into attention). V overwrites wt (dead).
    gemm_bt_r8<GF_BIAS><<<gN512, 256, 0, stream>>>(projp, inw + 512*512,  inb + 512,  nullptr, nullptr, Kbufp, 512, 512, 512, 512);
    gemm_bt_r8<GF_BIAS><<<gN512, 256, 0, stream>>>(projp, inw + 1024*512, inb + 1024, nullptr, nullptr, Vbufp, 512, 512, 512, 512);

    attn_fused_r8<<<2048, 256, 0, stream>>>(projp, inw, inb, Kbufp, Vbufp, attp);

    // enc = proj + att @ attn_out_w^T + attn_out_b   (enc overwrites K region)
    gemm_bt_r8<GF_BIAS|GF_ADD><<<gN512, 256, 0, stream>>>(attp, aow, aob, nullptr, projp, encp, 512, 512, 512, 512);

    // VQ
    row_sumsq_r8<<<4096, 256, 0, stream>>>(encp, asump);
    row_sumsq_r8<<<512,  256, 0, stream>>>(cb, cbbp);
    vq_argmin_r8<<<256, 256, 0, stream>>>(encp, cb, asump, cbbp, idxp);
    vq_loss_partial_r8<<<4096, 256, 0, stream>>>(encp, cb, idxp, lpart);

    // regime tables per codebook entry (R overwrites proj region, now dead)
    gemm_bt_r8<GF_BIAS|GF_RELU><<<dim3(32, 4),  256, 0, stream>>>(cb, r1w, r1b, nullptr, nullptr, hregp, 512, 512, 512, 256);
    gemm_bt_r8<GF_BIAS><<<dim3(32, 32), 256, 0, stream>>>(hregp, r2w, r2b, nullptr, nullptr, Rp, 256, 256, 256, 2048);
    softmax_rows_r8<<<2048, 256, 0, stream>>>(Rp);
    hash_table_r8<<<512, 256, 0, stream>>>(cb, hw, Tp);

    // ---- output writes (f32), every chunk fully covered each call ----
    write_loss_r8<<<1, 256, 0, stream>>>(lpart, out);
    write_regime_r8<<<131072, 256, 0, stream>>>(Rp, idxp, out);
    write_hash_r8<<<4096, 256, 0, stream>>>(Tp, idxp, out);
    write_idx_r8<<<64, 256, 0, stream>>>(idxp, out);
    write_quant_r8<<<32768, 256, 0, stream>>>(cb, idxp, out);
}

// Round 9
// 6993.482 us; speedup vs baseline: 1.3998x; 1.3998x over previous
//
#include <hip/hip_runtime.h>
#include <hip/hip_bf16.h>

// ---------------- problem constants ----------------
// B=32, S=512, D=512, K=2048, NHEADS=8, NHASH=4, HLEN=16; N = B*S = 16384.
// d_out is FLOAT32. Intermediates f32-stored.
// Inner products: f32 FMA over 16-elem chunks, f64 chunk combine (~3e-8 rel).
// VQ argmin: byte-identical to r8 (f64 dots, f32-absorbed compare, first-index
// tie-break) — this reproduced np's argmin including the tie token.

#define GF_BIAS 1
#define GF_RELU 2
#define GF_ADD  4
#define GF_POS  8
#define GF_ACC  16

// output layout (f32 elements), return order — total 43,008,001
static constexpr long long O_QUANT = 0LL;        // 8388608
static constexpr long long O_LOSS  = 8388608LL;  // 1
static constexpr long long O_IDX   = 8388609LL;  // 16384
static constexpr long long O_HASH  = 8404993LL;  // 1048576
static constexpr long long O_REG   = 9453569LL;  // 33554432
static constexpr long long O_END   = 43008001LL;

// workspace layout (f32 element offsets) — total 34,271,232 f32 = 130.7 MiB
static constexpr long long W_XP    = 0LL;
static constexpr long long W_CT    = 8388608LL;
static constexpr long long W_PROJ  = 16777216LL;
static constexpr long long W_VW    = 25165824LL;
static constexpr long long W_HREG  = 33554432LL;
static constexpr long long W_T     = 34078720LL;
static constexpr long long W_IDX   = 34209792LL;
static constexpr long long W_ASUM  = 34226176LL;
static constexpr long long W_CBB   = 34258944LL;
static constexpr long long W_LPART = 34263040LL;
static constexpr long long W_END   = 34271232LL;

// ---------------- generic GEMM, f32 chunk FMA / f64 chunk combine -------------
template<int FLAGS>
__global__ __launch_bounds__(256)
void gemm_bt_r9(const float* __restrict__ A, const float* __restrict__ Bm,
                const float* __restrict__ bias, const float* __restrict__ pos,
                const float* __restrict__ addsrc, float* __restrict__ C,
                int Kdim, int lda, int ldb, int ldc)
{
    __shared__ float As[16][68];
    __shared__ float Bs[16][68];
    const int tid = threadIdx.x;
    const int tx = tid & 15, ty = tid >> 4;
    const int bm = blockIdx.x * 64, bn = blockIdx.y * 64;
    const int lr = tid >> 2;          // 0..63
    const int lk = (tid & 3) << 2;    // 0,4,8,12
    const float* Arow = A  + (long long)(bm + lr) * lda + lk;
    const float* Brow = Bm + (long long)(bn + lr) * ldb + lk;
    double acc[4][4] = {};
    for (int k0 = 0; k0 < Kdim; k0 += 16) {
        float4 av = *(const float4*)(Arow + k0);
        float4 bv = *(const float4*)(Brow + k0);
        __syncthreads();
        As[lk+0][lr]=av.x; As[lk+1][lr]=av.y; As[lk+2][lr]=av.z; As[lk+3][lr]=av.w;
        Bs[lk+0][lr]=bv.x; Bs[lk+1][lr]=bv.y; Bs[lk+2][lr]=bv.z; Bs[lk+3][lr]=bv.w;
        __syncthreads();
        float cacc[4][4] = {};
        #pragma unroll
        for (int kk = 0; kk < 16; ++kk) {
            float a[4], b[4];
            #pragma unroll
            for (int i=0;i<4;i++) a[i] = As[kk][ty*4+i];
            #pragma unroll
            for (int j=0;j<4;j++) b[j] = Bs[kk][tx*4+j];
            #pragma unroll
            for (int i=0;i<4;i++)
                #pragma unroll
                for (int j=0;j<4;j++)
                    cacc[i][j] = fmaf(a[i], b[j], cacc[i][j]);
        }
        #pragma unroll
        for (int i=0;i<4;i++)
            #pragma unroll
            for (int j=0;j<4;j++)
                acc[i][j] += (double)cacc[i][j];
    }
    #pragma unroll
    for (int i=0;i<4;i++){
        const int row = bm + ty*4 + i;
        #pragma unroll
        for (int j=0;j<4;j++){
            const int col = bn + tx*4 + j;
            double v = acc[i][j];
            if constexpr (FLAGS & GF_BIAS) v += (double)bias[col];
            if constexpr (FLAGS & GF_POS)  v += (double)pos[(long long)(row & 511)*512 + col];
            if constexpr (FLAGS & GF_ADD)  v += (double)addsrc[(long long)row*ldc + col];
            if constexpr (FLAGS & GF_ACC)  v += (double)C[(long long)row*ldc + col];
            if constexpr (FLAGS & GF_RELU) v = (v > 0.0) ? v : 0.0;
            C[(long long)row*ldc + col] = (float)v;
        }
    }
}

// ---------------- conv1d as implicit GEMM, chunked accumulate ----------------
template<int KT>
__global__ __launch_bounds__(256)
void conv_relu_r9(const float* __restrict__ xp, const float* __restrict__ wt,
                  const float* __restrict__ bias, float* __restrict__ outp)
{
    constexpr int PAD = KT / 2;
    constexpr int KD  = KT * 512;
    __shared__ float As[16][68];
    __shared__ float Bs[16][68];
    const int tid = threadIdx.x;
    const int tx = tid & 15, ty = tid >> 4;
    const int bm = blockIdx.x * 64, bn = blockIdx.y * 64;
    const int lr = tid >> 2;
    const int lk = (tid & 3) << 2;
    const int n = bm + lr;
    const int s = n & 511;
    const float* Brow = wt + (long long)(bn + lr) * KD + lk;
    double acc[4][4] = {};
    for (int k0 = 0; k0 < KD; k0 += 16) {
        const int t  = k0 >> 9;
        const int i0 = (k0 & 511) + lk;
        const int sp = s + t - PAD;
        float4 av = make_float4(0.f,0.f,0.f,0.f);
        if (sp >= 0 && sp < 512)
            av = *(const float4*)(xp + (long long)(n + t - PAD)*512 + i0);
        float4 bv = *(const float4*)(Brow + k0);
        __syncthreads();
        As[lk+0][lr]=av.x; As[lk+1][lr]=av.y; As[lk+2][lr]=av.z; As[lk+3][lr]=av.w;
        Bs[lk+0][lr]=bv.x; Bs[lk+1][lr]=bv.y; Bs[lk+2][lr]=bv.z; Bs[lk+3][lr]=bv.w;
        __syncthreads();
        float cacc[4][4] = {};
        #pragma unroll
        for (int kk = 0; kk < 16; ++kk) {
            float a[4], b[4];
            #pragma unroll
            for (int i=0;i<4;i++) a[i] = As[kk][ty*4+i];
            #pragma unroll
            for (int j=0;j<4;j++) b[j] = Bs[kk][tx*4+j];
            #pragma unroll
            for (int i=0;i<4;i++)
                #pragma unroll
                for (int j=0;j<4;j++)
                    cacc[i][j] = fmaf(a[i], b[j], cacc[i][j]);
        }
        #pragma unroll
        for (int i=0;i<4;i++)
            #pragma unroll
            for (int j=0;j<4;j++)
                acc[i][j] += (double)cacc[i][j];
    }
    #pragma unroll
    for (int i=0;i<4;i++){
        const int row = bm + ty*4 + i;
        #pragma unroll
        for (int j=0;j<4;j++){
            const int col = bn + tx*4 + j;
            double v = acc[i][j] + (double)bias[col];
            outp[(long long)row*512 + col] = (float)((v > 0.0) ? v : 0.0);
        }
    }
}

// conv weight transpose: w[o][i][t] -> wt[o][t][i]
template<int KT>
__global__ __launch_bounds__(256)
void conv_w_tr_r9(const float* __restrict__ w, float* __restrict__ wt)
{
    long long i = (long long)blockIdx.x*256 + threadIdx.x;
    int o  = (int)(i / (512*KT));
    int rem= (int)(i % (512*KT));
    int t  = rem >> 9;
    int ii = rem & 511;
    wt[i] = w[(long long)o*512*KT + (long long)ii*KT + t];
}

// ---------------- fused attention (f32 math, f64 chunk combine) --------------
__global__ __launch_bounds__(256)
void attn_fused_r9(const float* __restrict__ proj, const float* __restrict__ inw,
                   const float* __restrict__ inb, const float* __restrict__ Kbuf,
                   const float* __restrict__ Vbuf, float* __restrict__ att)
{
    __shared__ float Qs[64][65];
    __shared__ float Kt[64][65];   // K tile, then P tile
    __shared__ float Vt[64][65];
    const int tid = threadIdx.x;
    const int tx = tid & 15, ty = tid >> 4;
    const int bid = blockIdx.x;
    const int qt = bid & 7, h = (bid >> 3) & 7, b = bid >> 6;
    const int row0 = b*512 + qt*64;
    const int lr = tid >> 2, lk = (tid & 3) << 2;

    { // Q = (proj @ Wq^T + bq) * 0.125, chunked accumulate
        double qa[4][4] = {};
        const float* Arow = proj + (long long)(row0 + lr)*512 + lk;
        const float* Brow = inw  + (long long)(h*64 + lr)*512 + lk;
        for (int k0 = 0; k0 < 512; k0 += 16) {
            float4 av = *(const float4*)(Arow + k0);
            float4 bv = *(const float4*)(Brow + k0);
            __syncthreads();
            Kt[lk+0][lr]=av.x; Kt[lk+1][lr]=av.y; Kt[lk+2][lr]=av.z; Kt[lk+3][lr]=av.w;
            Vt[lk+0][lr]=bv.x; Vt[lk+1][lr]=bv.y; Vt[lk+2][lr]=bv.z; Vt[lk+3][lr]=bv.w;
            __syncthreads();
            float c[4][4] = {};
            #pragma unroll
            for (int kk = 0; kk < 16; ++kk) {
                float a[4], bb[4];
                #pragma unroll
                for (int i=0;i<4;i++) a[i] = Kt[kk][ty*4+i];
                #pragma unroll
                for (int j=0;j<4;j++) bb[j] = Vt[kk][tx*4+j];
                #pragma unroll
                for (int i=0;i<4;i++)
                    #pragma unroll
                    for (int j=0;j<4;j++)
                        c[i][j] = fmaf(a[i], bb[j], c[i][j]);
            }
            #pragma unroll
            for (int i=0;i<4;i++)
                #pragma unroll
                for (int j=0;j<4;j++)
                    qa[i][j] += (double)c[i][j];
        }
        __syncthreads();
        #pragma unroll
        for (int i=0;i<4;i++)
            #pragma unroll
            for (int j=0;j<4;j++)
                Qs[ty*4+i][tx*4+j] = (float)((qa[i][j] + (double)inb[h*64 + tx*4+j]) * 0.125);
    }

    float m[4];
    double l[4], acc[4][4] = {};
    #pragma unroll
    for (int i=0;i<4;i++){ m[i] = -1e30f; l[i] = 0.0; }

    for (int kv = 0; kv < 512; kv += 64) {
        __syncthreads();
        #pragma unroll
        for (int u = 0; u < 16; ++u) {
            int e = u*256 + tid;
            int r = e >> 6, c = e & 63;
            Kt[r][c] = Kbuf[(long long)(b*512 + kv + r)*512 + h*64 + c];
            Vt[r][c] = Vbuf[(long long)(b*512 + kv + r)*512 + h*64 + c];
        }
        __syncthreads();
        // scores: chunked f32 FMA, f64 combine
        double scd[4][4] = {};
        for (int d0 = 0; d0 < 64; d0 += 16) {
            float c[4][4] = {};
            #pragma unroll
            for (int dd = 0; dd < 16; ++dd) {
                float a[4], bb[4];
                #pragma unroll
                for (int i=0;i<4;i++) a[i] = Qs[ty*4+i][d0+dd];
                #pragma unroll
                for (int j=0;j<4;j++) bb[j] = Kt[tx*4+j][d0+dd];
                #pragma unroll
                for (int i=0;i<4;i++)
                    #pragma unroll
                    for (int j=0;j<4;j++)
                        c[i][j] = fmaf(a[i], bb[j], c[i][j]);
            }
            #pragma unroll
            for (int i=0;i<4;i++)
                #pragma unroll
                for (int j=0;j<4;j++)
                    scd[i][j] += (double)c[i][j];
        }
        float sc[4][4];
        #pragma unroll
        for (int i=0;i<4;i++)
            #pragma unroll
            for (int j=0;j<4;j++)
                sc[i][j] = (float)scd[i][j];
        // online softmax: f32 max/exp, f64 sums
        #pragma unroll
        for (int i=0;i<4;i++){
            float tm = fmaxf(fmaxf(sc[i][0],sc[i][1]), fmaxf(sc[i][2],sc[i][3]));
            #pragma unroll
            for (int msk=1; msk<16; msk<<=1) tm = fmaxf(tm, __shfl_xor(tm, msk, 64));
            float mn = fmaxf(m[i], tm);
            float scale = expf(m[i] - mn);
            double rs = 0.0;
            #pragma unroll
            for (int j=0;j<4;j++){ float p = expf(sc[i][j]-mn); sc[i][j]=p; rs += (double)p; }
            #pragma unroll
            for (int msk=1; msk<16; msk<<=1) rs += __shfl_xor(rs, msk, 64);
            l[i] = l[i]*(double)scale + rs;
            m[i] = mn;
            #pragma unroll
            for (int j=0;j<4;j++) acc[i][j] *= (double)scale;
        }
        __syncthreads();   // all sc reads of Kt done; reuse Kt as P tile (f32)
        #pragma unroll
        for (int i=0;i<4;i++)
            #pragma unroll
            for (int j=0;j<4;j++)
                Kt[ty*4+i][tx*4+j] = sc[i][j];
        __syncthreads();
        // PV: chunked f32 FMA, f64 combine
        for (int d0 = 0; d0 < 64; d0 += 16) {
            float c[4][4] = {};
            #pragma unroll
            for (int dd = 0; dd < 16; ++dd) {
                float p[4], v[4];
                #pragma unroll
                for (int i=0;i<4;i++) p[i] = Kt[ty*4+i][d0+dd];
                #pragma unroll
                for (int j=0;j<4;j++) v[j] = Vt[d0+dd][tx*4+j];
                #pragma unroll
                for (int i=0;i<4;i++)
                    #pragma unroll
                    for (int j=0;j<4;j++)
                        c[i][j] = fmaf(p[i], v[j], c[i][j]);
            }
            #pragma unroll
            for (int i=0;i<4;i++)
                #pragma unroll
                for (int j=0;j<4;j++)
                    acc[i][j] += (double)c[i][j];
        }
    }
    #pragma unroll
    for (int i=0;i<4;i++)
        #pragma unroll
        for (int j=0;j<4;j++)
            att[(long long)(row0 + ty*4+i)*512 + h*64 + tx*4+j] = (float)(acc[i][j] / l[i]);
}

// ---------------- row sum of squares (f64), 512-col rows ---------------------
__global__ __launch_bounds__(256)
void row_sumsq_r9(const float* __restrict__ X, double* __restrict__ outp)
{
    const int row  = blockIdx.x*4 + (threadIdx.x >> 6);
    const int lane = threadIdx.x & 63;
    double s = 0.0;
    #pragma unroll
    for (int u = 0; u < 8; ++u) {
        float v = X[(long long)row*512 + lane + u*64];
        s += (double)v * (double)v;
    }
    #pragma unroll
    for (int msk = 32; msk; msk >>= 1) s += __shfl_xor(s, msk, 64);
    if (lane == 0) outp[row] = s;
}

// ---------------- VQ argmin: f64 dot, f32-ABSORBED dist compare (r8 verbatim) -
__global__ __launch_bounds__(256)
void vq_argmin_r9(const float* __restrict__ enc, const float* __restrict__ cb,
                  const double* __restrict__ Asum, const double* __restrict__ cbB,
                  int* __restrict__ idxout)
{
    __shared__ float Es[16][68];
    __shared__ float Cs[16][68];
    __shared__ float bv_s[64][17];
    __shared__ int   bi_s[64][17];
    const int tid = threadIdx.x;
    const int tx = tid & 15, ty = tid >> 4;
    const int lr = tid >> 2, lk = (tid & 3) << 2;
    const int bm = blockIdx.x * 64;
    float bestv[4]; int besti[4];
    #pragma unroll
    for (int i=0;i<4;i++){ bestv[i] = 3.0e38f; besti[i] = 2048; }

    for (int ct = 0; ct < 2048; ct += 64) {
        double macc[4][4] = {};
        for (int k0 = 0; k0 < 512; k0 += 16) {
            float4 av = *(const float4*)(enc + (long long)(bm + lr)*512 + k0 + lk);
            float4 bv = *(const float4*)(cb  + (long long)(ct + lr)*512 + k0 + lk);
            __syncthreads();
            Es[lk+0][lr]=av.x; Es[lk+1][lr]=av.y; Es[lk+2][lr]=av.z; Es[lk+3][lr]=av.w;
            Cs[lk+0][lr]=bv.x; Cs[lk+1][lr]=bv.y; Cs[lk+2][lr]=bv.z; Cs[lk+3][lr]=bv.w;
            __syncthreads();
            #pragma unroll
            for (int kk = 0; kk < 16; ++kk) {
                double a[4], b[4];
                #pragma unroll
                for (int i=0;i<4;i++) a[i] = (double)Es[kk][ty*4+i];
                #pragma unroll
                for (int j=0;j<4;j++) b[j] = (double)Cs[kk][tx*4+j];
                #pragma unroll
                for (int i=0;i<4;i++)
                    #pragma unroll
                    for (int j=0;j<4;j++)
                        macc[i][j] = fma(a[i], b[j], macc[i][j]);
            }
        }
        #pragma unroll
        for (int i=0;i<4;i++){
            const float anf = (float)Asum[bm + ty*4 + i];
            #pragma unroll
            for (int j=0;j<4;j++){
                const int ci = ct + tx*4 + j;
                const float bf  = (float)cbB[ci];
                const float s1  = anf + bf;                  // fl32(A+B)
                const float df  = (float)(2.0 * macc[i][j]); // fl32(2*dot)
                const float qd  = s1 - df;                   // fl32 combine
                if (qd < bestv[i] || (qd == bestv[i] && ci < besti[i])) {
                    bestv[i] = qd; besti[i] = ci;
                }
            }
        }
    }
    #pragma unroll
    for (int i=0;i<4;i++){ bv_s[ty*4+i][tx] = bestv[i]; bi_s[ty*4+i][tx] = besti[i]; }
    __syncthreads();
    if (tid < 64) {
        float bv = bv_s[tid][0]; int bi = bi_s[tid][0];
        #pragma unroll
        for (int x = 1; x < 16; ++x) {
            float v = bv_s[tid][x]; int ii = bi_s[tid][x];
            if (v < bv || (v == bv && ii < bi)) { bv = v; bi = ii; }
        }
        idxout[bm + tid] = bi & 2047;
    }
}

// ---------------- vq loss: two-stage, atomic-free ----------------------------
__global__ __launch_bounds__(256)
void vq_loss_partial_r9(const float* __restrict__ enc, const float* __restrict__ cb,
                        const int* __restrict__ idxp, double* __restrict__ part)
{
    __shared__ double red[4];
    const int row  = blockIdx.x*4 + (threadIdx.x >> 6);
    const int lane = threadIdx.x & 63;
    const int ci = idxp[row] & 2047;
    double s = 0.0;
    #pragma unroll
    for (int u = 0; u < 8; ++u) {
        int d = lane + u*64;
        double dv = (double)cb[(long long)ci*512 + d] - (double)enc[(long long)row*512 + d];
        s += dv * dv;
    }
    #pragma unroll
    for (int msk = 32; msk; msk >>= 1) s += __shfl_xor(s, msk, 64);
    if (lane == 0) red[threadIdx.x >> 6] = s;
    __syncthreads();
    if (threadIdx.x == 0)
        part[blockIdx.x] = red[0] + red[1] + red[2] + red[3];
}

// ---------------- regime softmax rows (in place) -----------------------------
__global__ __launch_bounds__(256)
void softmax_rows_r9(float* __restrict__ R)
{
    const int row = blockIdx.x;
    const int tid = threadIdx.x;
    __shared__ float  redf[256];
    __shared__ double redd[256];
    float* p = R + (long long)row * 2048;
    float mx = -1e30f;
    for (int c = tid; c < 2048; c += 256) mx = fmaxf(mx, p[c]);
    redf[tid] = mx; __syncthreads();
    for (int s2 = 128; s2; s2 >>= 1) { if (tid < s2) redf[tid] = fmaxf(redf[tid], redf[tid+s2]); __syncthreads(); }
    mx = redf[0];
    double sum = 0.0;
    for (int c = tid; c < 2048; c += 256) { float e = expf(p[c] - mx); p[c] = e; sum += e; }
    redd[tid] = sum; __syncthreads();
    for (int s2 = 128; s2; s2 >>= 1) { if (tid < s2) redd[tid] += redd[tid+s2]; __syncthreads(); }
    double tot = redd[0];
    for (int c = tid; c < 2048; c += 256) p[c] = (float)((double)p[c] / tot);
}

// ---------------- hash table per codebook entry ------------------------------
__global__ __launch_bounds__(256)
void hash_table_r9(const float* __restrict__ cb, const float* __restrict__ hw,
                   float* __restrict__ T)
{
    const int k = blockIdx.x*4 + (threadIdx.x >> 6);
    const int j = threadIdx.x & 63;
    double s = 0.0;
    for (int d = 0; d < 512; ++d)
        s += (double)cb[(long long)k*512 + d] * (double)hw[(long long)j*512 + d];
    T[(long long)k*64 + j] = (s > 0.0) ? 1.0f : 0.0f;
}

// ---------------- output writers (f32 d_out) ---------------------------------
__global__ void write_loss_r9(const double* __restrict__ part,
                              float* __restrict__ out)
{
    __shared__ double red[256];
    double s = 0.0;
    for (int i = threadIdx.x; i < 4096; i += 256) s += part[i];
    red[threadIdx.x] = s; __syncthreads();
    for (int s2 = 128; s2; s2 >>= 1) {
        if (threadIdx.x < s2) red[threadIdx.x] += red[threadIdx.x + s2];
        __syncthreads();
    }
    if (threadIdx.x == 0)
        out[O_LOSS] = (float)(1.25 * red[0] / 8388608.0);
}

__global__ __launch_bounds__(256)
void write_regime_r9(const float* __restrict__ R, const int* __restrict__ idxp,
                     float* __restrict__ out)
{
    long long i = (long long)blockIdx.x*256 + threadIdx.x;
    if (i >= 33554432LL) return;
    int n = (int)(i >> 11), c = (int)(i & 2047);
    int ci = idxp[n] & 2047;
    out[O_REG + i] = R[(long long)ci*2048 + c];
}

__global__ __launch_bounds__(256)
void write_hash_r9(const float* __restrict__ T, const int* __restrict__ idxp,
                   float* __restrict__ out)
{
    long long i = (long long)blockIdx.x*256 + threadIdx.x;
    if (i >= 1048576LL) return;
    int n = (int)(i >> 6), j = (int)(i & 63);
    int ci = idxp[n] & 2047;
    out[O_HASH + i] = T[(long long)ci*64 + j];
}

__global__ __launch_bounds__(256)
void write_idx_r9(const int* __restrict__ idxp, float* __restrict__ out)
{
    int n = blockIdx.x*256 + threadIdx.x;
    if (n >= 16384) return;
    out[O_IDX + n] = (float)(idxp[n] & 2047);
}

__global__ __launch_bounds__(256)
void write_quant_r9(const float* __restrict__ cb, const int* __restrict__ idxp,
                    float* __restrict__ out)
{
    long long i = (long long)blockIdx.x*256 + threadIdx.x;
    if (i >= 8388608LL) return;
    int n = (int)(i >> 9), d = (int)(i & 511);
    int ci = idxp[n] & 2047;
    out[O_QUANT + i] = cb[(long long)ci*512 + d];
}

// ---------------- launcher ----------------------------------------------------
extern "C" void kernel_launch(void* const* d_in, const int* in_sizes, int n_in,
                              void* d_out, int out_size, void* d_ws, size_t ws_size,
                              hipStream_t stream)
{
    (void)in_sizes; (void)n_in; (void)out_size;
    const float* market = (const float*)d_in[0];
    const float* W_in   = (const float*)d_in[1];
    const float* b_in   = (const float*)d_in[2];
    const float* pos    = (const float*)d_in[3];
    const float* c3w = (const float*)d_in[4];  const float* c3b = (const float*)d_in[5];
    const float* c5w = (const float*)d_in[6];  const float* c5b = (const float*)d_in[7];
    const float* c7w = (const float*)d_in[8];  const float* c7b = (const float*)d_in[9];
    const float* c9w = (const float*)d_in[10]; const float* c9b = (const float*)d_in[11];
    const float* msw = (const float*)d_in[12]; const float* msb = (const float*)d_in[13];
    const float* inw = (const float*)d_in[14]; const float* inb = (const float*)d_in[15];
    const float* aow = (const float*)d_in[16]; const float* aob = (const float*)d_in[17];
    const float* cb  = (const float*)d_in[18]; const float* hw  = (const float*)d_in[19];
    const float* r1w = (const float*)d_in[20]; const float* r1b = (const float*)d_in[21];
    const float* r2w = (const float*)d_in[22]; const float* r2b = (const float*)d_in[23];

    if (ws_size < (size_t)W_END * sizeof(float)) return; // insufficient scratch

    float* ws    = (float*)d_ws;
    float* xp    = ws + W_XP;
    float* convt = ws + W_CT;
    float* projp = ws + W_PROJ;
    float* wt3   = ws + W_VW;        // conv weights time-share the V region
    float* wt5   = wt3 + 512*512*3;
    float* wt7   = wt5 + 512*512*5;
    float* wt9   = wt7 + 512*512*7;
    float* Vbufp = ws + W_VW;
    float* hregp = ws + W_HREG;
    float* Tp    = ws + W_T;
    int*    idxp  = (int*)(ws + W_IDX);
    double* asump = (double*)(ws + W_ASUM);
    double* cbbp  = (double*)(ws + W_CBB);
    double* lpart = (double*)(ws + W_LPART);

    float* out = (float*)d_out;   // f32 output buffer

    float* attp  = xp;      // xp dead after conv9
    float* Kbufp = convt;   // conv_tmp dead after last ms gemm
    float* encp  = convt;   // K dead after attn
    float* Rp    = projp;   // proj dead after enc gemm

    // conv weight transposes
    conv_w_tr_r9<3><<<3072, 256, 0, stream>>>(c3w, wt3);
    conv_w_tr_r9<5><<<5120, 256, 0, stream>>>(c5w, wt5);
    conv_w_tr_r9<7><<<7168, 256, 0, stream>>>(c7w, wt7);
    conv_w_tr_r9<9><<<9216, 256, 0, stream>>>(c9w, wt9);

    const dim3 gN512(256, 8);

    // xp = market @ W_in^T + b_in + pos_enc
    gemm_bt_r9<GF_BIAS|GF_POS><<<gN512, 256, 0, stream>>>(market, W_in, b_in, pos, nullptr, xp, 512, 512, 512, 512);

    // proj = sum_c relu(conv_c(xp)) @ msW_c^T (+ bias on first)
    conv_relu_r9<3><<<gN512, 256, 0, stream>>>(xp, wt3, c3b, convt);
    gemm_bt_r9<GF_BIAS><<<gN512, 256, 0, stream>>>(convt, msw + 0*512, msb, nullptr, nullptr, projp, 512, 512, 2048, 512);
    conv_relu_r9<5><<<gN512, 256, 0, stream>>>(xp, wt5, c5b, convt);
    gemm_bt_r9<GF_ACC><<<gN512, 256, 0, stream>>>(convt, msw + 1*512, nullptr, nullptr, nullptr, projp, 512, 512, 2048, 512);
    conv_relu_r9<7><<<gN512, 256, 0, stream>>>(xp, wt7, c7b, convt);
    gemm_bt_r9<GF_ACC><<<gN512, 256, 0, stream>>>(convt, msw + 2*512, nullptr, nullptr, nullptr, projp, 512, 512, 2048, 512);
    conv_relu_r9<9><<<gN512, 256, 0, stream>>>(xp, wt9, c9b, convt);
    gemm_bt_r9<GF_ACC><<<gN512, 256, 0, stream>>>(convt, msw + 3*512, nullptr, nullptr, nullptr, projp, 512, 512, 2048, 512);

    // K, V projections (Q fused into attention). V overwrites wt (dead).
    gemm_bt_r9<GF_BIAS><<<gN512, 256, 0, stream>>>(projp, inw + 512*512,  inb + 512,  nullptr, nullptr, Kbufp, 512, 512, 512, 512);
    gemm_bt_r9<GF_BIAS><<<gN512, 256, 0, stream>>>(projp, inw + 1024*512, inb + 1024, nullptr, nullptr, Vbufp, 512, 512, 512, 512);

    attn_fused_r9<<<2048, 256, 0, stream>>>(projp, inw, inb, Kbufp, Vbufp, attp);

    // enc = proj + att @ attn_out_w^T + attn_out_b   (enc overwrites K region)
    gemm_bt_r9<GF_BIAS|GF_ADD><<<gN512, 256, 0, stream>>>(attp, aow, aob, nullptr, projp, encp, 512, 512, 512, 512);

    // VQ
    row_sumsq_r9<<<4096, 256, 0, stream>>>(encp, asump);
    row_sumsq_r9<<<512,  256, 0, stream>>>(cb, cbbp);
    vq_argmin_r9<<<256, 256, 0, stream>>>(encp, cb, asump, cbbp, idxp);
    vq_loss_partial_r9<<<4096, 256, 0, stream>>>(encp, cb, idxp, lpart);

    // regime tables per codebook entry (R overwrites proj region, now dead)
    gemm_bt_r9<GF_BIAS|GF_RELU><<<dim3(32, 4),  256, 0, stream>>>(cb, r1w, r1b, nullptr, nullptr, hregp, 512, 512, 512, 256);
    gemm_bt_r9<GF_BIAS><<<dim3(32, 32), 256, 0, stream>>>(hregp, r2w, r2b, nullptr, nullptr, Rp, 256, 256, 256, 2048);
    softmax_rows_r9<<<2048, 256, 0, stream>>>(Rp);
    hash_table_r9<<<512, 256, 0, stream>>>(cb, hw, Tp);

    // ---- output writes (f32), every chunk fully covered each call ----
    write_loss_r9<<<1, 256, 0, stream>>>(lpart, out);
    write_regime_r9<<<131072, 256, 0, stream>>>(Rp, idxp, out);
    write_hash_r9<<<4096, 256, 0, stream>>>(Tp, idxp, out);
    write_idx_r9<<<64, 256, 0, stream>>>(idxp, out);
    write_quant_r9<<<32768, 256, 0, stream>>>(cb, idxp, out);
}

// Round 10
// 5601.600 us; speedup vs baseline: 1.7476x; 1.2485x over previous
//
#include <hip/hip_runtime.h>
#include <hip/hip_bf16.h>

// ---------------- problem constants ----------------
// B=32, S=512, D=512, K=2048, NHEADS=8, NHASH=4, HLEN=16; N = B*S = 16384.
// d_out is FLOAT32. Intermediates f32-stored.
// Inner products: f32 FMA over 16-elem chunks, f64 chunk combine.
// VQ argmin: chunked-f32 dots, f32-absorbed dist compare, first-index
// tie-break; ct-split over 4 blocks + lexicographic partial reduce.

#define GF_BIAS 1
#define GF_RELU 2
#define GF_ADD  4
#define GF_POS  8
#define GF_ACC  16

// output layout (f32 elements), return order — total 43,008,001
static constexpr long long O_QUANT = 0LL;        // 8388608
static constexpr long long O_LOSS  = 8388608LL;  // 1
static constexpr long long O_IDX   = 8388609LL;  // 16384
static constexpr long long O_HASH  = 8404993LL;  // 1048576
static constexpr long long O_REG   = 9453569LL;  // 33554432
static constexpr long long O_END   = 43008001LL;

// workspace layout (f32 element offsets) — total 34,402,304 f32 = 131.2 MiB
static constexpr long long W_XP    = 0LL;
static constexpr long long W_CT    = 8388608LL;
static constexpr long long W_PROJ  = 16777216LL;
static constexpr long long W_VW    = 25165824LL;
static constexpr long long W_HREG  = 33554432LL;
static constexpr long long W_T     = 34078720LL;
static constexpr long long W_IDX   = 34209792LL;
static constexpr long long W_ASUM  = 34226176LL;  // 16384 f64
static constexpr long long W_CBB   = 34258944LL;  // 2048 f64
static constexpr long long W_LPART = 34263040LL;  // 4096 f64
static constexpr long long W_PBV   = 34271232LL;  // 4*16384 f32 partial best val
static constexpr long long W_PBI   = 34336768LL;  // 4*16384 int partial best idx
static constexpr long long W_END   = 34402304LL;

// ---------------- generic GEMM, f32 chunk FMA / f64 chunk combine -------------
template<int FLAGS>
__global__ __launch_bounds__(256)
void gemm_bt_r10(const float* __restrict__ A, const float* __restrict__ Bm,
                 const float* __restrict__ bias, const float* __restrict__ pos,
                 const float* __restrict__ addsrc, float* __restrict__ C,
                 int Kdim, int lda, int ldb, int ldc)
{
    __shared__ float As[16][68];
    __shared__ float Bs[16][68];
    const int tid = threadIdx.x;
    const int tx = tid & 15, ty = tid >> 4;
    const int bm = blockIdx.x * 64, bn = blockIdx.y * 64;
    const int lr = tid >> 2;          // 0..63
    const int lk = (tid & 3) << 2;    // 0,4,8,12
    const float* Arow = A  + (long long)(bm + lr) * lda + lk;
    const float* Brow = Bm + (long long)(bn + lr) * ldb + lk;
    double acc[4][4] = {};
    for (int k0 = 0; k0 < Kdim; k0 += 16) {
        float4 av = *(const float4*)(Arow + k0);
        float4 bv = *(const float4*)(Brow + k0);
        __syncthreads();
        As[lk+0][lr]=av.x; As[lk+1][lr]=av.y; As[lk+2][lr]=av.z; As[lk+3][lr]=av.w;
        Bs[lk+0][lr]=bv.x; Bs[lk+1][lr]=bv.y; Bs[lk+2][lr]=bv.z; Bs[lk+3][lr]=bv.w;
        __syncthreads();
        float cacc[4][4] = {};
        #pragma unroll
        for (int kk = 0; kk < 16; ++kk) {
            float a[4], b[4];
            #pragma unroll
            for (int i=0;i<4;i++) a[i] = As[kk][ty*4+i];
            #pragma unroll
            for (int j=0;j<4;j++) b[j] = Bs[kk][tx*4+j];
            #pragma unroll
            for (int i=0;i<4;i++)
                #pragma unroll
                for (int j=0;j<4;j++)
                    cacc[i][j] = fmaf(a[i], b[j], cacc[i][j]);
        }
        #pragma unroll
        for (int i=0;i<4;i++)
            #pragma unroll
            for (int j=0;j<4;j++)
                acc[i][j] += (double)cacc[i][j];
    }
    #pragma unroll
    for (int i=0;i<4;i++){
        const int row = bm + ty*4 + i;
        #pragma unroll
        for (int j=0;j<4;j++){
            const int col = bn + tx*4 + j;
            double v = acc[i][j];
            if constexpr (FLAGS & GF_BIAS) v += (double)bias[col];
            if constexpr (FLAGS & GF_POS)  v += (double)pos[(long long)(row & 511)*512 + col];
            if constexpr (FLAGS & GF_ADD)  v += (double)addsrc[(long long)row*ldc + col];
            if constexpr (FLAGS & GF_ACC)  v += (double)C[(long long)row*ldc + col];
            if constexpr (FLAGS & GF_RELU) v = (v > 0.0) ? v : 0.0;
            C[(long long)row*ldc + col] = (float)v;
        }
    }
}

// ---------------- conv1d as implicit GEMM, chunked accumulate ----------------
template<int KT>
__global__ __launch_bounds__(256)
void conv_relu_r10(const float* __restrict__ xp, const float* __restrict__ wt,
                   const float* __restrict__ bias, float* __restrict__ outp)
{
    constexpr int PAD = KT / 2;
    constexpr int KD  = KT * 512;
    __shared__ float As[16][68];
    __shared__ float Bs[16][68];
    const int tid = threadIdx.x;
    const int tx = tid & 15, ty = tid >> 4;
    const int bm = blockIdx.x * 64, bn = blockIdx.y * 64;
    const int lr = tid >> 2;
    const int lk = (tid & 3) << 2;
    const int n = bm + lr;
    const int s = n & 511;
    const float* Brow = wt + (long long)(bn + lr) * KD + lk;
    double acc[4][4] = {};
    for (int k0 = 0; k0 < KD; k0 += 16) {
        const int t  = k0 >> 9;
        const int i0 = (k0 & 511) + lk;
        const int sp = s + t - PAD;
        float4 av = make_float4(0.f,0.f,0.f,0.f);
        if (sp >= 0 && sp < 512)
            av = *(const float4*)(xp + (long long)(n + t - PAD)*512 + i0);
        float4 bv = *(const float4*)(Brow + k0);
        __syncthreads();
        As[lk+0][lr]=av.x; As[lk+1][lr]=av.y; As[lk+2][lr]=av.z; As[lk+3][lr]=av.w;
        Bs[lk+0][lr]=bv.x; Bs[lk+1][lr]=bv.y; Bs[lk+2][lr]=bv.z; Bs[lk+3][lr]=bv.w;
        __syncthreads();
        float cacc[4][4] = {};
        #pragma unroll
        for (int kk = 0; kk < 16; ++kk) {
            float a[4], b[4];
            #pragma unroll
            for (int i=0;i<4;i++) a[i] = As[kk][ty*4+i];
            #pragma unroll
            for (int j=0;j<4;j++) b[j] = Bs[kk][tx*4+j];
            #pragma unroll
            for (int i=0;i<4;i++)
                #pragma unroll
                for (int j=0;j<4;j++)
                    cacc[i][j] = fmaf(a[i], b[j], cacc[i][j]);
        }
        #pragma unroll
        for (int i=0;i<4;i++)
            #pragma unroll
            for (int j=0;j<4;j++)
                acc[i][j] += (double)cacc[i][j];
    }
    #pragma unroll
    for (int i=0;i<4;i++){
        const int row = bm + ty*4 + i;
        #pragma unroll
        for (int j=0;j<4;j++){
            const int col = bn + tx*4 + j;
            double v = acc[i][j] + (double)bias[col];
            outp[(long long)row*512 + col] = (float)((v > 0.0) ? v : 0.0);
        }
    }
}

// conv weight transpose: w[o][i][t] -> wt[o][t][i]
template<int KT>
__global__ __launch_bounds__(256)
void conv_w_tr_r10(const float* __restrict__ w, float* __restrict__ wt)
{
    long long i = (long long)blockIdx.x*256 + threadIdx.x;
    int o  = (int)(i / (512*KT));
    int rem= (int)(i % (512*KT));
    int t  = rem >> 9;
    int ii = rem & 511;
    wt[i] = w[(long long)o*512*KT + (long long)ii*KT + t];
}

// ---------------- fused attention (f32 math, f64 chunk combine) --------------
__global__ __launch_bounds__(256)
void attn_fused_r10(const float* __restrict__ proj, const float* __restrict__ inw,
                    const float* __restrict__ inb, const float* __restrict__ Kbuf,
                    const float* __restrict__ Vbuf, float* __restrict__ att)
{
    __shared__ float Qs[64][65];
    __shared__ float Kt[64][65];   // K tile, then P tile
    __shared__ float Vt[64][65];
    const int tid = threadIdx.x;
    const int tx = tid & 15, ty = tid >> 4;
    const int bid = blockIdx.x;
    const int qt = bid & 7, h = (bid >> 3) & 7, b = bid >> 6;
    const int row0 = b*512 + qt*64;
    const int lr = tid >> 2, lk = (tid & 3) << 2;

    { // Q = (proj @ Wq^T + bq) * 0.125, chunked accumulate
        double qa[4][4] = {};
        const float* Arow = proj + (long long)(row0 + lr)*512 + lk;
        const float* Brow = inw  + (long long)(h*64 + lr)*512 + lk;
        for (int k0 = 0; k0 < 512; k0 += 16) {
            float4 av = *(const float4*)(Arow + k0);
            float4 bv = *(const float4*)(Brow + k0);
            __syncthreads();
            Kt[lk+0][lr]=av.x; Kt[lk+1][lr]=av.y; Kt[lk+2][lr]=av.z; Kt[lk+3][lr]=av.w;
            Vt[lk+0][lr]=bv.x; Vt[lk+1][lr]=bv.y; Vt[lk+2][lr]=bv.z; Vt[lk+3][lr]=bv.w;
            __syncthreads();
            float c[4][4] = {};
            #pragma unroll
            for (int kk = 0; kk < 16; ++kk) {
                float a[4], bb[4];
                #pragma unroll
                for (int i=0;i<4;i++) a[i] = Kt[kk][ty*4+i];
                #pragma unroll
                for (int j=0;j<4;j++) bb[j] = Vt[kk][tx*4+j];
                #pragma unroll
                for (int i=0;i<4;i++)
                    #pragma unroll
                    for (int j=0;j<4;j++)
                        c[i][j] = fmaf(a[i], bb[j], c[i][j]);
            }
            #pragma unroll
            for (int i=0;i<4;i++)
                #pragma unroll
                for (int j=0;j<4;j++)
                    qa[i][j] += (double)c[i][j];
        }
        __syncthreads();
        #pragma unroll
        for (int i=0;i<4;i++)
            #pragma unroll
            for (int j=0;j<4;j++)
                Qs[ty*4+i][tx*4+j] = (float)((qa[i][j] + (double)inb[h*64 + tx*4+j]) * 0.125);
    }

    float m[4];
    double l[4], acc[4][4] = {};
    #pragma unroll
    for (int i=0;i<4;i++){ m[i] = -1e30f; l[i] = 0.0; }

    for (int kv = 0; kv < 512; kv += 64) {
        __syncthreads();
        #pragma unroll
        for (int u = 0; u < 16; ++u) {
            int e = u*256 + tid;
            int r = e >> 6, c = e & 63;
            Kt[r][c] = Kbuf[(long long)(b*512 + kv + r)*512 + h*64 + c];
            Vt[r][c] = Vbuf[(long long)(b*512 + kv + r)*512 + h*64 + c];
        }
        __syncthreads();
        // scores: chunked f32 FMA, f64 combine
        double scd[4][4] = {};
        for (int d0 = 0; d0 < 64; d0 += 16) {
            float c[4][4] = {};
            #pragma unroll
            for (int dd = 0; dd < 16; ++dd) {
                float a[4], bb[4];
                #pragma unroll
                for (int i=0;i<4;i++) a[i] = Qs[ty*4+i][d0+dd];
                #pragma unroll
                for (int j=0;j<4;j++) bb[j] = Kt[tx*4+j][d0+dd];
                #pragma unroll
                for (int i=0;i<4;i++)
                    #pragma unroll
                    for (int j=0;j<4;j++)
                        c[i][j] = fmaf(a[i], bb[j], c[i][j]);
            }
            #pragma unroll
            for (int i=0;i<4;i++)
                #pragma unroll
                for (int j=0;j<4;j++)
                    scd[i][j] += (double)c[i][j];
        }
        float sc[4][4];
        #pragma unroll
        for (int i=0;i<4;i++)
            #pragma unroll
            for (int j=0;j<4;j++)
                sc[i][j] = (float)scd[i][j];
        // online softmax: f32 max/exp, f64 sums
        #pragma unroll
        for (int i=0;i<4;i++){
            float tm = fmaxf(fmaxf(sc[i][0],sc[i][1]), fmaxf(sc[i][2],sc[i][3]));
            #pragma unroll
            for (int msk=1; msk<16; msk<<=1) tm = fmaxf(tm, __shfl_xor(tm, msk, 64));
            float mn = fmaxf(m[i], tm);
            float scale = expf(m[i] - mn);
            double rs = 0.0;
            #pragma unroll
            for (int j=0;j<4;j++){ float p = expf(sc[i][j]-mn); sc[i][j]=p; rs += (double)p; }
            #pragma unroll
            for (int msk=1; msk<16; msk<<=1) rs += __shfl_xor(rs, msk, 64);
            l[i] = l[i]*(double)scale + rs;
            m[i] = mn;
            #pragma unroll
            for (int j=0;j<4;j++) acc[i][j] *= (double)scale;
        }
        __syncthreads();   // all sc reads of Kt done; reuse Kt as P tile (f32)
        #pragma unroll
        for (int i=0;i<4;i++)
            #pragma unroll
            for (int j=0;j<4;j++)
                Kt[ty*4+i][tx*4+j] = sc[i][j];
        __syncthreads();
        // PV: chunked f32 FMA, f64 combine
        for (int d0 = 0; d0 < 64; d0 += 16) {
            float c[4][4] = {};
            #pragma unroll
            for (int dd = 0; dd < 16; ++dd) {
                float p[4], v[4];
                #pragma unroll
                for (int i=0;i<4;i++) p[i] = Kt[ty*4+i][d0+dd];
                #pragma unroll
                for (int j=0;j<4;j++) v[j] = Vt[d0+dd][tx*4+j];
                #pragma unroll
                for (int i=0;i<4;i++)
                    #pragma unroll
                    for (int j=0;j<4;j++)
                        c[i][j] = fmaf(p[i], v[j], c[i][j]);
            }
            #pragma unroll
            for (int i=0;i<4;i++)
                #pragma unroll
                for (int j=0;j<4;j++)
                    acc[i][j] += (double)c[i][j];
        }
    }
    #pragma unroll
    for (int i=0;i<4;i++)
        #pragma unroll
        for (int j=0;j<4;j++)
            att[(long long)(row0 + ty*4+i)*512 + h*64 + tx*4+j] = (float)(acc[i][j] / l[i]);
}

// ---------------- row sum of squares (f64), 512-col rows ---------------------
__global__ __launch_bounds__(256)
void row_sumsq_r10(const float* __restrict__ X, double* __restrict__ outp)
{
    const int row  = blockIdx.x*4 + (threadIdx.x >> 6);
    const int lane = threadIdx.x & 63;
    double s = 0.0;
    #pragma unroll
    for (int u = 0; u < 8; ++u) {
        float v = X[(long long)row*512 + lane + u*64];
        s += (double)v * (double)v;
    }
    #pragma unroll
    for (int msk = 32; msk; msk >>= 1) s += __shfl_xor(s, msk, 64);
    if (lane == 0) outp[row] = s;
}

// ---------------- VQ argmin: ct-split x4, chunked-f32 dots, absorbed compare -
// blockIdx.y = codebook quarter. Each block: 64 tokens x 512 entries.
// Per-quarter (bestv,besti) partials; vq_reduce combines lexicographically,
// preserving np.argmin first-index tie-break.
__global__ __launch_bounds__(256)
void vq_argmin_r10(const float* __restrict__ enc, const float* __restrict__ cb,
                   const double* __restrict__ Asum, const double* __restrict__ cbB,
                   float* __restrict__ pbv, int* __restrict__ pbi)
{
    __shared__ float Es[16][68];
    __shared__ float Cs[16][68];
    __shared__ float bv_s[64][17];
    __shared__ int   bi_s[64][17];
    const int tid = threadIdx.x;
    const int tx = tid & 15, ty = tid >> 4;
    const int lr = tid >> 2, lk = (tid & 3) << 2;
    const int bm  = blockIdx.x * 64;
    const int ct0 = blockIdx.y * 512;
    float bestv[4]; int besti[4];
    #pragma unroll
    for (int i=0;i<4;i++){ bestv[i] = 3.0e38f; besti[i] = 2048; }

    for (int ct = ct0; ct < ct0 + 512; ct += 64) {
        double macc[4][4] = {};
        for (int k0 = 0; k0 < 512; k0 += 16) {
            float4 av = *(const float4*)(enc + (long long)(bm + lr)*512 + k0 + lk);
            float4 bv = *(const float4*)(cb  + (long long)(ct + lr)*512 + k0 + lk);
            __syncthreads();
            Es[lk+0][lr]=av.x; Es[lk+1][lr]=av.y; Es[lk+2][lr]=av.z; Es[lk+3][lr]=av.w;
            Cs[lk+0][lr]=bv.x; Cs[lk+1][lr]=bv.y; Cs[lk+2][lr]=bv.z; Cs[lk+3][lr]=bv.w;
            __syncthreads();
            float cacc[4][4] = {};
            #pragma unroll
            for (int kk = 0; kk < 16; ++kk) {
                float a[4], b[4];
                #pragma unroll
                for (int i=0;i<4;i++) a[i] = Es[kk][ty*4+i];
                #pragma unroll
                for (int j=0;j<4;j++) b[j] = Cs[kk][tx*4+j];
                #pragma unroll
                for (int i=0;i<4;i++)
                    #pragma unroll
                    for (int j=0;j<4;j++)
                        cacc[i][j] = fmaf(a[i], b[j], cacc[i][j]);
            }
            #pragma unroll
            for (int i=0;i<4;i++)
                #pragma unroll
                for (int j=0;j<4;j++)
                    macc[i][j] += (double)cacc[i][j];
        }
        #pragma unroll
        for (int i=0;i<4;i++){
            const float anf = (float)Asum[bm + ty*4 + i];
            #pragma unroll
            for (int j=0;j<4;j++){
                const int ci = ct + tx*4 + j;
                const float bf  = (float)cbB[ci];
                const float s1  = anf + bf;                  // fl32(A+B)
                const float df  = (float)(2.0 * macc[i][j]); // fl32(2*dot)
                const float qd  = s1 - df;                   // fl32 combine
                if (qd < bestv[i] || (qd == bestv[i] && ci < besti[i])) {
                    bestv[i] = qd; besti[i] = ci;
                }
            }
        }
    }
    #pragma unroll
    for (int i=0;i<4;i++){ bv_s[ty*4+i][tx] = bestv[i]; bi_s[ty*4+i][tx] = besti[i]; }
    __syncthreads();
    if (tid < 64) {
        float bv = bv_s[tid][0]; int bi = bi_s[tid][0];
        #pragma unroll
        for (int x = 1; x < 16; ++x) {
            float v = bv_s[tid][x]; int ii = bi_s[tid][x];
            if (v < bv || (v == bv && ii < bi)) { bv = v; bi = ii; }
        }
        pbv[(long long)blockIdx.y*16384 + bm + tid] = bv;
        pbi[(long long)blockIdx.y*16384 + bm + tid] = bi;
    }
}

__global__ __launch_bounds__(256)
void vq_reduce_r10(const float* __restrict__ pbv, const int* __restrict__ pbi,
                   int* __restrict__ idxout)
{
    int n = blockIdx.x*256 + threadIdx.x;
    if (n >= 16384) return;
    float bv = pbv[n]; int bi = pbi[n];
    #pragma unroll
    for (int q = 1; q < 4; ++q) {
        float v = pbv[q*16384 + n]; int ii = pbi[q*16384 + n];
        if (v < bv || (v == bv && ii < bi)) { bv = v; bi = ii; }
    }
    idxout[n] = bi & 2047;
}

// ---------------- vq loss: two-stage, atomic-free ----------------------------
__global__ __launch_bounds__(256)
void vq_loss_partial_r10(const float* __restrict__ enc, const float* __restrict__ cb,
                         const int* __restrict__ idxp, double* __restrict__ part)
{
    __shared__ double red[4];
    const int row  = blockIdx.x*4 + (threadIdx.x >> 6);
    const int lane = threadIdx.x & 63;
    const int ci = idxp[row] & 2047;
    double s = 0.0;
    #pragma unroll
    for (int u = 0; u < 8; ++u) {
        int d = lane + u*64;
        double dv = (double)cb[(long long)ci*512 + d] - (double)enc[(long long)row*512 + d];
        s += dv * dv;
    }
    #pragma unroll
    for (int msk = 32; msk; msk >>= 1) s += __shfl_xor(s, msk, 64);
    if (lane == 0) red[threadIdx.x >> 6] = s;
    __syncthreads();
    if (threadIdx.x == 0)
        part[blockIdx.x] = red[0] + red[1] + red[2] + red[3];
}

// ---------------- regime softmax rows (in place) -----------------------------
__global__ __launch_bounds__(256)
void softmax_rows_r10(float* __restrict__ R)
{
    const int row = blockIdx.x;
    const int tid = threadIdx.x;
    __shared__ float  redf[256];
    __shared__ double redd[256];
    float* p = R + (long long)row * 2048;
    float mx = -1e30f;
    for (int c = tid; c < 2048; c += 256) mx = fmaxf(mx, p[c]);
    redf[tid] = mx; __syncthreads();
    for (int s2 = 128; s2; s2 >>= 1) { if (tid < s2) redf[tid] = fmaxf(redf[tid], redf[tid+s2]); __syncthreads(); }
    mx = redf[0];
    double sum = 0.0;
    for (int c = tid; c < 2048; c += 256) { float e = expf(p[c] - mx); p[c] = e; sum += e; }
    redd[tid] = sum; __syncthreads();
    for (int s2 = 128; s2; s2 >>= 1) { if (tid < s2) redd[tid] += redd[tid+s2]; __syncthreads(); }
    double tot = redd[0];
    for (int c = tid; c < 2048; c += 256) p[c] = (float)((double)p[c] / tot);
}

// ---------------- hash table per codebook entry ------------------------------
__global__ __launch_bounds__(256)
void hash_table_r10(const float* __restrict__ cb, const float* __restrict__ hw,
                    float* __restrict__ T)
{
    const int k = blockIdx.x*4 + (threadIdx.x >> 6);
    const int j = threadIdx.x & 63;
    double s = 0.0;
    for (int d = 0; d < 512; ++d)
        s += (double)cb[(long long)k*512 + d] * (double)hw[(long long)j*512 + d];
    T[(long long)k*64 + j] = (s > 0.0) ? 1.0f : 0.0f;
}

// ---------------- output writers (f32 d_out) ---------------------------------
__global__ void write_loss_r10(const double* __restrict__ part,
                               float* __restrict__ out)
{
    __shared__ double red[256];
    double s = 0.0;
    for (int i = threadIdx.x; i < 4096; i += 256) s += part[i];
    red[threadIdx.x] = s; __syncthreads();
    for (int s2 = 128; s2; s2 >>= 1) {
        if (threadIdx.x < s2) red[threadIdx.x] += red[threadIdx.x + s2];
        __syncthreads();
    }
    if (threadIdx.x == 0)
        out[O_LOSS] = (float)(1.25 * red[0] / 8388608.0);
}

__global__ __launch_bounds__(256)
void write_regime_r10(const float* __restrict__ R, const int* __restrict__ idxp,
                      float* __restrict__ out)
{
    long long i = (long long)blockIdx.x*256 + threadIdx.x;
    if (i >= 33554432LL) return;
    int n = (int)(i >> 11), c = (int)(i & 2047);
    int ci = idxp[n] & 2047;
    out[O_REG + i] = R[(long long)ci*2048 + c];
}

__global__ __launch_bounds__(256)
void write_hash_r10(const float* __restrict__ T, const int* __restrict__ idxp,
                    float* __restrict__ out)
{
    long long i = (long long)blockIdx.x*256 + threadIdx.x;
    if (i >= 1048576LL) return;
    int n = (int)(i >> 6), j = (int)(i & 63);
    int ci = idxp[n] & 2047;
    out[O_HASH + i] = T[(long long)ci*64 + j];
}

__global__ __launch_bounds__(256)
void write_idx_r10(const int* __restrict__ idxp, float* __restrict__ out)
{
    int n = blockIdx.x*256 + threadIdx.x;
    if (n >= 16384) return;
    out[O_IDX + n] = (float)(idxp[n] & 2047);
}

__global__ __launch_bounds__(256)
void write_quant_r10(const float* __restrict__ cb, const int* __restrict__ idxp,
                     float* __restrict__ out)
{
    long long i = (long long)blockIdx.x*256 + threadIdx.x;
    if (i >= 8388608LL) return;
    int n = (int)(i >> 9), d = (int)(i & 511);
    int ci = idxp[n] & 2047;
    out[O_QUANT + i] = cb[(long long)ci*512 + d];
}

// ---------------- launcher ----------------------------------------------------
extern "C" void kernel_launch(void* const* d_in, const int* in_sizes, int n_in,
                              void* d_out, int out_size, void* d_ws, size_t ws_size,
                              hipStream_t stream)
{
    (void)in_sizes; (void)n_in; (void)out_size;
    const float* market = (const float*)d_in[0];
    const float* W_in   = (const float*)d_in[1];
    const float* b_in   = (const float*)d_in[2];
    const float* pos    = (const float*)d_in[3];
    const float* c3w = (const float*)d_in[4];  const float* c3b = (const float*)d_in[5];
    const float* c5w = (const float*)d_in[6];  const float* c5b = (const float*)d_in[7];
    const float* c7w = (const float*)d_in[8];  const float* c7b = (const float*)d_in[9];
    const float* c9w = (const float*)d_in[10]; const float* c9b = (const float*)d_in[11];
    const float* msw = (const float*)d_in[12]; const float* msb = (const float*)d_in[13];
    const float* inw = (const float*)d_in[14]; const float* inb = (const float*)d_in[15];
    const float* aow = (const float*)d_in[16]; const float* aob = (const float*)d_in[17];
    const float* cb  = (const float*)d_in[18]; const float* hw  = (const float*)d_in[19];
    const float* r1w = (const float*)d_in[20]; const float* r1b = (const float*)d_in[21];
    const float* r2w = (const float*)d_in[22]; const float* r2b = (const float*)d_in[23];

    if (ws_size < (size_t)W_END * sizeof(float)) return; // insufficient scratch

    float* ws    = (float*)d_ws;
    float* xp    = ws + W_XP;
    float* convt = ws + W_CT;
    float* projp = ws + W_PROJ;
    float* wt3   = ws + W_VW;        // conv weights time-share the V region
    float* wt5   = wt3 + 512*512*3;
    float* wt7   = wt5 + 512*512*5;
    float* wt9   = wt7 + 512*512*7;
    float* Vbufp = ws + W_VW;
    float* hregp = ws + W_HREG;
    float* Tp    = ws + W_T;
    int*    idxp  = (int*)(ws + W_IDX);
    double* asump = (double*)(ws + W_ASUM);
    double* cbbp  = (double*)(ws + W_CBB);
    double* lpart = (double*)(ws + W_LPART);
    float*  pbvp  = ws + W_PBV;
    int*    pbip  = (int*)(ws + W_PBI);

    float* out = (float*)d_out;   // f32 output buffer

    float* attp  = xp;      // xp dead after conv9
    float* Kbufp = convt;   // conv_tmp dead after last ms gemm
    float* encp  = convt;   // K dead after attn
    float* Rp    = projp;   // proj dead after enc gemm

    // conv weight transposes
    conv_w_tr_r10<3><<<3072, 256, 0, stream>>>(c3w, wt3);
    conv_w_tr_r10<5><<<5120, 256, 0, stream>>>(c5w, wt5);
    conv_w_tr_r10<7><<<7168, 256, 0, stream>>>(c7w, wt7);
    conv_w_tr_r10<9><<<9216, 256, 0, stream>>>(c9w, wt9);

    const dim3 gN512(256, 8);

    // xp = market @ W_in^T + b_in + pos_enc
    gemm_bt_r10<GF_BIAS|GF_POS><<<gN512, 256, 0, stream>>>(market, W_in, b_in, pos, nullptr, xp, 512, 512, 512, 512);

    // proj = sum_c relu(conv_c(xp)) @ msW_c^T (+ bias on first)
    conv_relu_r10<3><<<gN512, 256, 0, stream>>>(xp, wt3, c3b, convt);
    gemm_bt_r10<GF_BIAS><<<gN512, 256, 0, stream>>>(convt, msw + 0*512, msb, nullptr, nullptr, projp, 512, 512, 2048, 512);
    conv_relu_r10<5><<<gN512, 256, 0, stream>>>(xp, wt5, c5b, convt);
    gemm_bt_r10<GF_ACC><<<gN512, 256, 0, stream>>>(convt, msw + 1*512, nullptr, nullptr, nullptr, projp, 512, 512, 2048, 512);
    conv_relu_r10<7><<<gN512, 256, 0, stream>>>(xp, wt7, c7b, convt);
    gemm_bt_r10<GF_ACC><<<gN512, 256, 0, stream>>>(convt, msw + 2*512, nullptr, nullptr, nullptr, projp, 512, 512, 2048, 512);
    conv_relu_r10<9><<<gN512, 256, 0, stream>>>(xp, wt9, c9b, convt);
    gemm_bt_r10<GF_ACC><<<gN512, 256, 0, stream>>>(convt, msw + 3*512, nullptr, nullptr, nullptr, projp, 512, 512, 2048, 512);

    // K, V projections (Q fused into attention). V overwrites wt (dead).
    gemm_bt_r10<GF_BIAS><<<gN512, 256, 0, stream>>>(projp, inw + 512*512,  inb + 512,  nullptr, nullptr, Kbufp, 512, 512, 512, 512);
    gemm_bt_r10<GF_BIAS><<<gN512, 256, 0, stream>>>(projp, inw + 1024*512, inb + 1024, nullptr, nullptr, Vbufp, 512, 512, 512, 512);

    attn_fused_r10<<<2048, 256, 0, stream>>>(projp, inw, inb, Kbufp, Vbufp, attp);

    // enc = proj + att @ attn_out_w^T + attn_out_b   (enc overwrites K region)
    gemm_bt_r10<GF_BIAS|GF_ADD><<<gN512, 256, 0, stream>>>(attp, aow, aob, nullptr, projp, encp, 512, 512, 512, 512);

    // VQ
    row_sumsq_r10<<<4096, 256, 0, stream>>>(encp, asump);
    row_sumsq_r10<<<512,  256, 0, stream>>>(cb, cbbp);
    vq_argmin_r10<<<dim3(256, 4), 256, 0, stream>>>(encp, cb, asump, cbbp, pbvp, pbip);
    vq_reduce_r10<<<64, 256, 0, stream>>>(pbvp, pbip, idxp);
    vq_loss_partial_r10<<<4096, 256, 0, stream>>>(encp, cb, idxp, lpart);

    // regime tables per codebook entry (R overwrites proj region, now dead)
    gemm_bt_r10<GF_BIAS|GF_RELU><<<dim3(32, 4),  256, 0, stream>>>(cb, r1w, r1b, nullptr, nullptr, hregp, 512, 512, 512, 256);
    gemm_bt_r10<GF_BIAS><<<dim3(32, 32), 256, 0, stream>>>(hregp, r2w, r2b, nullptr, nullptr, Rp, 256, 256, 256, 2048);
    softmax_rows_r10<<<2048, 256, 0, stream>>>(Rp);
    hash_table_r10<<<512, 256, 0, stream>>>(cb, hw, Tp);

    // ---- output writes (f32), every chunk fully covered each call ----
    write_loss_r10<<<1, 256, 0, stream>>>(lpart, out);
    write_regime_r10<<<131072, 256, 0, stream>>>(Rp, idxp, out);
    write_hash_r10<<<4096, 256, 0, stream>>>(Tp, idxp, out);
    write_idx_r10<<<64, 256, 0, stream>>>(idxp, out);
    write_quant_r10<<<32768, 256, 0, stream>>>(cb, idxp, out);
}

// Round 11
// 5511.077 us; speedup vs baseline: 1.7763x; 1.0164x over previous
//
#include <hip/hip_runtime.h>
#include <hip/hip_bf16.h>

// ---------------- problem constants ----------------
// B=32, S=512, D=512, K=2048, NHEADS=8, NHASH=4, HLEN=16; N = B*S = 16384.
// d_out is FLOAT32. Intermediates f32-stored.
// Inner products: f32 FMA over 16-elem chunks, f64 chunk combine —
// EXACT same rounding sequence as r10 (bit-identical outputs); r11 only
// restructures staging (BK=32, one barrier pair per 32 k).

#define GF_BIAS 1
#define GF_RELU 2
#define GF_ADD  4
#define GF_POS  8
#define GF_ACC  16

// output layout (f32 elements), return order — total 43,008,001
static constexpr long long O_QUANT = 0LL;        // 8388608
static constexpr long long O_LOSS  = 8388608LL;  // 1
static constexpr long long O_IDX   = 8388609LL;  // 16384
static constexpr long long O_HASH  = 8404993LL;  // 1048576
static constexpr long long O_REG   = 9453569LL;  // 33554432
static constexpr long long O_END   = 43008001LL;

// workspace layout (f32 element offsets) — total 34,402,304 f32 = 131.2 MiB
static constexpr long long W_XP    = 0LL;
static constexpr long long W_CT    = 8388608LL;
static constexpr long long W_PROJ  = 16777216LL;
static constexpr long long W_VW    = 25165824LL;
static constexpr long long W_HREG  = 33554432LL;
static constexpr long long W_T     = 34078720LL;
static constexpr long long W_IDX   = 34209792LL;
static constexpr long long W_ASUM  = 34226176LL;  // 16384 f64
static constexpr long long W_CBB   = 34258944LL;  // 2048 f64
static constexpr long long W_LPART = 34263040LL;  // 4096 f64
static constexpr long long W_PBV   = 34271232LL;  // 4*16384 f32 partial best val
static constexpr long long W_PBI   = 34336768LL;  // 4*16384 int partial best idx
static constexpr long long W_END   = 34402304LL;

// ---------------- generic GEMM: BK=32 staging, 16-chunk f32 / f64 combine ----
template<int FLAGS>
__global__ __launch_bounds__(256)
void gemm_bt_r11(const float* __restrict__ A, const float* __restrict__ Bm,
                 const float* __restrict__ bias, const float* __restrict__ pos,
                 const float* __restrict__ addsrc, float* __restrict__ C,
                 int Kdim, int lda, int ldb, int ldc)
{
    __shared__ float As[32][68];
    __shared__ float Bs[32][68];
    const int tid = threadIdx.x;
    const int tx = tid & 15, ty = tid >> 4;
    const int bm = blockIdx.x * 64, bn = blockIdx.y * 64;
    const int lr = tid >> 2;          // 0..63
    const int lk = (tid & 3) << 2;    // 0,4,8,12
    const float* Arow = A  + (long long)(bm + lr) * lda + lk;
    const float* Brow = Bm + (long long)(bn + lr) * ldb + lk;
    double acc[4][4] = {};
    for (int k0 = 0; k0 < Kdim; k0 += 32) {
        float4 av0 = *(const float4*)(Arow + k0);
        float4 av1 = *(const float4*)(Arow + k0 + 16);
        float4 bv0 = *(const float4*)(Brow + k0);
        float4 bv1 = *(const float4*)(Brow + k0 + 16);
        __syncthreads();
        As[lk+0][lr]=av0.x; As[lk+1][lr]=av0.y; As[lk+2][lr]=av0.z; As[lk+3][lr]=av0.w;
        As[lk+16][lr]=av1.x; As[lk+17][lr]=av1.y; As[lk+18][lr]=av1.z; As[lk+19][lr]=av1.w;
        Bs[lk+0][lr]=bv0.x; Bs[lk+1][lr]=bv0.y; Bs[lk+2][lr]=bv0.z; Bs[lk+3][lr]=bv0.w;
        Bs[lk+16][lr]=bv1.x; Bs[lk+17][lr]=bv1.y; Bs[lk+18][lr]=bv1.z; Bs[lk+19][lr]=bv1.w;
        __syncthreads();
        // chunk 0 (k0..k0+15) — identical rounding sequence to r10
        {
            float cacc[4][4] = {};
            #pragma unroll
            for (int kk = 0; kk < 16; ++kk) {
                float a[4], b[4];
                #pragma unroll
                for (int i=0;i<4;i++) a[i] = As[kk][ty*4+i];
                #pragma unroll
                for (int j=0;j<4;j++) b[j] = Bs[kk][tx*4+j];
                #pragma unroll
                for (int i=0;i<4;i++)
                    #pragma unroll
                    for (int j=0;j<4;j++)
                        cacc[i][j] = fmaf(a[i], b[j], cacc[i][j]);
            }
            #pragma unroll
            for (int i=0;i<4;i++)
                #pragma unroll
                for (int j=0;j<4;j++)
                    acc[i][j] += (double)cacc[i][j];
        }
        // chunk 1 (k0+16..k0+31)
        {
            float cacc[4][4] = {};
            #pragma unroll
            for (int kk = 16; kk < 32; ++kk) {
                float a[4], b[4];
                #pragma unroll
                for (int i=0;i<4;i++) a[i] = As[kk][ty*4+i];
                #pragma unroll
                for (int j=0;j<4;j++) b[j] = Bs[kk][tx*4+j];
                #pragma unroll
                for (int i=0;i<4;i++)
                    #pragma unroll
                    for (int j=0;j<4;j++)
                        cacc[i][j] = fmaf(a[i], b[j], cacc[i][j]);
            }
            #pragma unroll
            for (int i=0;i<4;i++)
                #pragma unroll
                for (int j=0;j<4;j++)
                    acc[i][j] += (double)cacc[i][j];
        }
    }
    #pragma unroll
    for (int i=0;i<4;i++){
        const int row = bm + ty*4 + i;
        #pragma unroll
        for (int j=0;j<4;j++){
            const int col = bn + tx*4 + j;
            double v = acc[i][j];
            if constexpr (FLAGS & GF_BIAS) v += (double)bias[col];
            if constexpr (FLAGS & GF_POS)  v += (double)pos[(long long)(row & 511)*512 + col];
            if constexpr (FLAGS & GF_ADD)  v += (double)addsrc[(long long)row*ldc + col];
            if constexpr (FLAGS & GF_ACC)  v += (double)C[(long long)row*ldc + col];
            if constexpr (FLAGS & GF_RELU) v = (v > 0.0) ? v : 0.0;
            C[(long long)row*ldc + col] = (float)v;
        }
    }
}

// ---------------- conv1d as implicit GEMM, BK=32 staging ---------------------
// 512 % 32 == 0 so a 32-block never crosses a t boundary.
template<int KT>
__global__ __launch_bounds__(256)
void conv_relu_r11(const float* __restrict__ xp, const float* __restrict__ wt,
                   const float* __restrict__ bias, float* __restrict__ outp)
{
    constexpr int PAD = KT / 2;
    constexpr int KD  = KT * 512;
    __shared__ float As[32][68];
    __shared__ float Bs[32][68];
    const int tid = threadIdx.x;
    const int tx = tid & 15, ty = tid >> 4;
    const int bm = blockIdx.x * 64, bn = blockIdx.y * 64;
    const int lr = tid >> 2;
    const int lk = (tid & 3) << 2;
    const int n = bm + lr;
    const int s = n & 511;
    const float* xr   = xp + (long long)(n - PAD) * 512;   // row base (t=0)
    const float* Brow = wt + (long long)(bn + lr) * KD + lk;
    double acc[4][4] = {};
    for (int k0 = 0; k0 < KD; k0 += 32) {
        const int t  = k0 >> 9;
        const int i0 = (k0 & 511) + lk;
        const int sp = s + t - PAD;
        float4 av0 = make_float4(0.f,0.f,0.f,0.f);
        float4 av1 = make_float4(0.f,0.f,0.f,0.f);
        if (sp >= 0 && sp < 512) {
            const float* p = xr + (long long)t*512 + i0;
            av0 = *(const float4*)(p);
            av1 = *(const float4*)(p + 16);
        }
        float4 bv0 = *(const float4*)(Brow + k0);
        float4 bv1 = *(const float4*)(Brow + k0 + 16);
        __syncthreads();
        As[lk+0][lr]=av0.x; As[lk+1][lr]=av0.y; As[lk+2][lr]=av0.z; As[lk+3][lr]=av0.w;
        As[lk+16][lr]=av1.x; As[lk+17][lr]=av1.y; As[lk+18][lr]=av1.z; As[lk+19][lr]=av1.w;
        Bs[lk+0][lr]=bv0.x; Bs[lk+1][lr]=bv0.y; Bs[lk+2][lr]=bv0.z; Bs[lk+3][lr]=bv0.w;
        Bs[lk+16][lr]=bv1.x; Bs[lk+17][lr]=bv1.y; Bs[lk+18][lr]=bv1.z; Bs[lk+19][lr]=bv1.w;
        __syncthreads();
        {
            float cacc[4][4] = {};
            #pragma unroll
            for (int kk = 0; kk < 16; ++kk) {
                float a[4], b[4];
                #pragma unroll
                for (int i=0;i<4;i++) a[i] = As[kk][ty*4+i];
                #pragma unroll
                for (int j=0;j<4;j++) b[j] = Bs[kk][tx*4+j];
                #pragma unroll
                for (int i=0;i<4;i++)
                    #pragma unroll
                    for (int j=0;j<4;j++)
                        cacc[i][j] = fmaf(a[i], b[j], cacc[i][j]);
            }
            #pragma unroll
            for (int i=0;i<4;i++)
                #pragma unroll
                for (int j=0;j<4;j++)
                    acc[i][j] += (double)cacc[i][j];
        }
        {
            float cacc[4][4] = {};
            #pragma unroll
            for (int kk = 16; kk < 32; ++kk) {
                float a[4], b[4];
                #pragma unroll
                for (int i=0;i<4;i++) a[i] = As[kk][ty*4+i];
                #pragma unroll
                for (int j=0;j<4;j++) b[j] = Bs[kk][tx*4+j];
                #pragma unroll
                for (int i=0;i<4;i++)
                    #pragma unroll
                    for (int j=0;j<4;j++)
                        cacc[i][j] = fmaf(a[i], b[j], cacc[i][j]);
            }
            #pragma unroll
            for (int i=0;i<4;i++)
                #pragma unroll
                for (int j=0;j<4;j++)
                    acc[i][j] += (double)cacc[i][j];
        }
    }
    #pragma unroll
    for (int i=0;i<4;i++){
        const int row = bm + ty*4 + i;
        #pragma unroll
        for (int j=0;j<4;j++){
            const int col = bn + tx*4 + j;
            double v = acc[i][j] + (double)bias[col];
            outp[(long long)row*512 + col] = (float)((v > 0.0) ? v : 0.0);
        }
    }
}

// conv weight transpose: w[o][i][t] -> wt[o][t][i]
template<int KT>
__global__ __launch_bounds__(256)
void conv_w_tr_r11(const float* __restrict__ w, float* __restrict__ wt)
{
    long long i = (long long)blockIdx.x*256 + threadIdx.x;
    int o  = (int)(i / (512*KT));
    int rem= (int)(i % (512*KT));
    int t  = rem >> 9;
    int ii = rem & 511;
    wt[i] = w[(long long)o*512*KT + (long long)ii*KT + t];
}

// ---------------- fused attention (unchanged from r10) -----------------------
__global__ __launch_bounds__(256)
void attn_fused_r11(const float* __restrict__ proj, const float* __restrict__ inw,
                    const float* __restrict__ inb, const float* __restrict__ Kbuf,
                    const float* __restrict__ Vbuf, float* __restrict__ att)
{
    __shared__ float Qs[64][65];
    __shared__ float Kt[64][65];   // K tile, then P tile
    __shared__ float Vt[64][65];
    const int tid = threadIdx.x;
    const int tx = tid & 15, ty = tid >> 4;
    const int bid = blockIdx.x;
    const int qt = bid & 7, h = (bid >> 3) & 7, b = bid >> 6;
    const int row0 = b*512 + qt*64;
    const int lr = tid >> 2, lk = (tid & 3) << 2;

    { // Q = (proj @ Wq^T + bq) * 0.125, chunked accumulate
        double qa[4][4] = {};
        const float* Arow = proj + (long long)(row0 + lr)*512 + lk;
        const float* Brow = inw  + (long long)(h*64 + lr)*512 + lk;
        for (int k0 = 0; k0 < 512; k0 += 16) {
            float4 av = *(const float4*)(Arow + k0);
            float4 bv = *(const float4*)(Brow + k0);
            __syncthreads();
            Kt[lk+0][lr]=av.x; Kt[lk+1][lr]=av.y; Kt[lk+2][lr]=av.z; Kt[lk+3][lr]=av.w;
            Vt[lk+0][lr]=bv.x; Vt[lk+1][lr]=bv.y; Vt[lk+2][lr]=bv.z; Vt[lk+3][lr]=bv.w;
            __syncthreads();
            float c[4][4] = {};
            #pragma unroll
            for (int kk = 0; kk < 16; ++kk) {
                float a[4], bb[4];
                #pragma unroll
                for (int i=0;i<4;i++) a[i] = Kt[kk][ty*4+i];
                #pragma unroll
                for (int j=0;j<4;j++) bb[j] = Vt[kk][tx*4+j];
                #pragma unroll
                for (int i=0;i<4;i++)
                    #pragma unroll
                    for (int j=0;j<4;j++)
                        c[i][j] = fmaf(a[i], bb[j], c[i][j]);
            }
            #pragma unroll
            for (int i=0;i<4;i++)
                #pragma unroll
                for (int j=0;j<4;j++)
                    qa[i][j] += (double)c[i][j];
        }
        __syncthreads();
        #pragma unroll
        for (int i=0;i<4;i++)
            #pragma unroll
            for (int j=0;j<4;j++)
                Qs[ty*4+i][tx*4+j] = (float)((qa[i][j] + (double)inb[h*64 + tx*4+j]) * 0.125);
    }

    float m[4];
    double l[4], acc[4][4] = {};
    #pragma unroll
    for (int i=0;i<4;i++){ m[i] = -1e30f; l[i] = 0.0; }

    for (int kv = 0; kv < 512; kv += 64) {
        __syncthreads();
        #pragma unroll
        for (int u = 0; u < 16; ++u) {
            int e = u*256 + tid;
            int r = e >> 6, c = e & 63;
            Kt[r][c] = Kbuf[(long long)(b*512 + kv + r)*512 + h*64 + c];
            Vt[r][c] = Vbuf[(long long)(b*512 + kv + r)*512 + h*64 + c];
        }
        __syncthreads();
        // scores: chunked f32 FMA, f64 combine
        double scd[4][4] = {};
        for (int d0 = 0; d0 < 64; d0 += 16) {
            float c[4][4] = {};
            #pragma unroll
            for (int dd = 0; dd < 16; ++dd) {
                float a[4], bb[4];
                #pragma unroll
                for (int i=0;i<4;i++) a[i] = Qs[ty*4+i][d0+dd];
                #pragma unroll
                for (int j=0;j<4;j++) bb[j] = Kt[tx*4+j][d0+dd];
                #pragma unroll
                for (int i=0;i<4;i++)
                    #pragma unroll
                    for (int j=0;j<4;j++)
                        c[i][j] = fmaf(a[i], bb[j], c[i][j]);
            }
            #pragma unroll
            for (int i=0;i<4;i++)
                #pragma unroll
                for (int j=0;j<4;j++)
                    scd[i][j] += (double)c[i][j];
        }
        float sc[4][4];
        #pragma unroll
        for (int i=0;i<4;i++)
            #pragma unroll
            for (int j=0;j<4;j++)
                sc[i][j] = (float)scd[i][j];
        // online softmax: f32 max/exp, f64 sums
        #pragma unroll
        for (int i=0;i<4;i++){
            float tm = fmaxf(fmaxf(sc[i][0],sc[i][1]), fmaxf(sc[i][2],sc[i][3]));
            #pragma unroll
            for (int msk=1; msk<16; msk<<=1) tm = fmaxf(tm, __shfl_xor(tm, msk, 64));
            float mn = fmaxf(m[i], tm);
            float scale = expf(m[i] - mn);
            double rs = 0.0;
            #pragma unroll
            for (int j=0;j<4;j++){ float p = expf(sc[i][j]-mn); sc[i][j]=p; rs += (double)p; }
            #pragma unroll
            for (int msk=1; msk<16; msk<<=1) rs += __shfl_xor(rs, msk, 64);
            l[i] = l[i]*(double)scale + rs;
            m[i] = mn;
            #pragma unroll
            for (int j=0;j<4;j++) acc[i][j] *= (double)scale;
        }
        __syncthreads();   // all sc reads of Kt done; reuse Kt as P tile (f32)
        #pragma unroll
        for (int i=0;i<4;i++)
            #pragma unroll
            for (int j=0;j<4;j++)
                Kt[ty*4+i][tx*4+j] = sc[i][j];
        __syncthreads();
        // PV: chunked f32 FMA, f64 combine
        for (int d0 = 0; d0 < 64; d0 += 16) {
            float c[4][4] = {};
            #pragma unroll
            for (int dd = 0; dd < 16; ++dd) {
                float p[4], v[4];
                #pragma unroll
                for (int i=0;i<4;i++) p[i] = Kt[ty*4+i][d0+dd];
                #pragma unroll
                for (int j=0;j<4;j++) v[j] = Vt[d0+dd][tx*4+j];
                #pragma unroll
                for (int i=0;i<4;i++)
                    #pragma unroll
                    for (int j=0;j<4;j++)
                        c[i][j] = fmaf(p[i], v[j], c[i][j]);
            }
            #pragma unroll
            for (int i=0;i<4;i++)
                #pragma unroll
                for (int j=0;j<4;j++)
                    acc[i][j] += (double)c[i][j];
        }
    }
    #pragma unroll
    for (int i=0;i<4;i++)
        #pragma unroll
        for (int j=0;j<4;j++)
            att[(long long)(row0 + ty*4+i)*512 + h*64 + tx*4+j] = (float)(acc[i][j] / l[i]);
}

// ---------------- row sum of squares (f64), 512-col rows ---------------------
__global__ __launch_bounds__(256)
void row_sumsq_r11(const float* __restrict__ X, double* __restrict__ outp)
{
    const int row  = blockIdx.x*4 + (threadIdx.x >> 6);
    const int lane = threadIdx.x & 63;
    double s = 0.0;
    #pragma unroll
    for (int u = 0; u < 8; ++u) {
        float v = X[(long long)row*512 + lane + u*64];
        s += (double)v * (double)v;
    }
    #pragma unroll
    for (int msk = 32; msk; msk >>= 1) s += __shfl_xor(s, msk, 64);
    if (lane == 0) outp[row] = s;
}

// ---------------- VQ argmin: ct-split x4, BK=32 staging, same dot rounding ---
__global__ __launch_bounds__(256)
void vq_argmin_r11(const float* __restrict__ enc, const float* __restrict__ cb,
                   const double* __restrict__ Asum, const double* __restrict__ cbB,
                   float* __restrict__ pbv, int* __restrict__ pbi)
{
    __shared__ float Es[32][68];
    __shared__ float Cs[32][68];
    __shared__ float bv_s[64][17];
    __shared__ int   bi_s[64][17];
    const int tid = threadIdx.x;
    const int tx = tid & 15, ty = tid >> 4;
    const int lr = tid >> 2, lk = (tid & 3) << 2;
    const int bm  = blockIdx.x * 64;
    const int ct0 = blockIdx.y * 512;
    float bestv[4]; int besti[4];
    #pragma unroll
    for (int i=0;i<4;i++){ bestv[i] = 3.0e38f; besti[i] = 2048; }

    for (int ct = ct0; ct < ct0 + 512; ct += 64) {
        double macc[4][4] = {};
        for (int k0 = 0; k0 < 512; k0 += 32) {
            float4 av0 = *(const float4*)(enc + (long long)(bm + lr)*512 + k0 + lk);
            float4 av1 = *(const float4*)(enc + (long long)(bm + lr)*512 + k0 + 16 + lk);
            float4 bv0 = *(const float4*)(cb  + (long long)(ct + lr)*512 + k0 + lk);
            float4 bv1 = *(const float4*)(cb  + (long long)(ct + lr)*512 + k0 + 16 + lk);
            __syncthreads();
            Es[lk+0][lr]=av0.x; Es[lk+1][lr]=av0.y; Es[lk+2][lr]=av0.z; Es[lk+3][lr]=av0.w;
            Es[lk+16][lr]=av1.x; Es[lk+17][lr]=av1.y; Es[lk+18][lr]=av1.z; Es[lk+19][lr]=av1.w;
            Cs[lk+0][lr]=bv0.x; Cs[lk+1][lr]=bv0.y; Cs[lk+2][lr]=bv0.z; Cs[lk+3][lr]=bv0.w;
            Cs[lk+16][lr]=bv1.x; Cs[lk+17][lr]=bv1.y; Cs[lk+18][lr]=bv1.z; Cs[lk+19][lr]=bv1.w;
            __syncthreads();
            {
                float cacc[4][4] = {};
                #pragma unroll
                for (int kk = 0; kk < 16; ++kk) {
                    float a[4], b[4];
                    #pragma unroll
                    for (int i=0;i<4;i++) a[i] = Es[kk][ty*4+i];
                    #pragma unroll
                    for (int j=0;j<4;j++) b[j] = Cs[kk][tx*4+j];
                    #pragma unroll
                    for (int i=0;i<4;i++)
                        #pragma unroll
                        for (int j=0;j<4;j++)
                            cacc[i][j] = fmaf(a[i], b[j], cacc[i][j]);
                }
                #pragma unroll
                for (int i=0;i<4;i++)
                    #pragma unroll
                    for (int j=0;j<4;j++)
                        macc[i][j] += (double)cacc[i][j];
            }
            {
                float cacc[4][4] = {};
                #pragma unroll
                for (int kk = 16; kk < 32; ++kk) {
                    float a[4], b[4];
                    #pragma unroll
                    for (int i=0;i<4;i++) a[i] = Es[kk][ty*4+i];
                    #pragma unroll
                    for (int j=0;j<4;j++) b[j] = Cs[kk][tx*4+j];
                    #pragma unroll
                    for (int i=0;i<4;i++)
                        #pragma unroll
                        for (int j=0;j<4;j++)
                            cacc[i][j] = fmaf(a[i], b[j], cacc[i][j]);
                }
                #pragma unroll
                for (int i=0;i<4;i++)
                    #pragma unroll
                    for (int j=0;j<4;j++)
                        macc[i][j] += (double)cacc[i][j];
            }
        }
        #pragma unroll
        for (int i=0;i<4;i++){
            const float anf = (float)Asum[bm + ty*4 + i];
            #pragma unroll
            for (int j=0;j<4;j++){
                const int ci = ct + tx*4 + j;
                const float bf  = (float)cbB[ci];
                const float s1  = anf + bf;                  // fl32(A+B)
                const float df  = (float)(2.0 * macc[i][j]); // fl32(2*dot)
                const float qd  = s1 - df;                   // fl32 combine
                if (qd < bestv[i] || (qd == bestv[i] && ci < besti[i])) {
                    bestv[i] = qd; besti[i] = ci;
                }
            }
        }
    }
    #pragma unroll
    for (int i=0;i<4;i++){ bv_s[ty*4+i][tx] = bestv[i]; bi_s[ty*4+i][tx] = besti[i]; }
    __syncthreads();
    if (tid < 64) {
        float bv = bv_s[tid][0]; int bi = bi_s[tid][0];
        #pragma unroll
        for (int x = 1; x < 16; ++x) {
            float v = bv_s[tid][x]; int ii = bi_s[tid][x];
            if (v < bv || (v == bv && ii < bi)) { bv = v; bi = ii; }
        }
        pbv[(long long)blockIdx.y*16384 + bm + tid] = bv;
        pbi[(long long)blockIdx.y*16384 + bm + tid] = bi;
    }
}

__global__ __launch_bounds__(256)
void vq_reduce_r11(const float* __restrict__ pbv, const int* __restrict__ pbi,
                   int* __restrict__ idxout)
{
    int n = blockIdx.x*256 + threadIdx.x;
    if (n >= 16384) return;
    float bv = pbv[n]; int bi = pbi[n];
    #pragma unroll
    for (int q = 1; q < 4; ++q) {
        float v = pbv[q*16384 + n]; int ii = pbi[q*16384 + n];
        if (v < bv || (v == bv && ii < bi)) { bv = v; bi = ii; }
    }
    idxout[n] = bi & 2047;
}

// ---------------- vq loss: two-stage, atomic-free ----------------------------
__global__ __launch_bounds__(256)
void vq_loss_partial_r11(const float* __restrict__ enc, const float* __restrict__ cb,
                         const int* __restrict__ idxp, double* __restrict__ part)
{
    __shared__ double red[4];
    const int row  = blockIdx.x*4 + (threadIdx.x >> 6);
    const int lane = threadIdx.x & 63;
    const int ci = idxp[row] & 2047;
    double s = 0.0;
    #pragma unroll
    for (int u = 0; u < 8; ++u) {
        int d = lane + u*64;
        double dv = (double)cb[(long long)ci*512 + d] - (double)enc[(long long)row*512 + d];
        s += dv * dv;
    }
    #pragma unroll
    for (int msk = 32; msk; msk >>= 1) s += __shfl_xor(s, msk, 64);
    if (lane == 0) red[threadIdx.x >> 6] = s;
    __syncthreads();
    if (threadIdx.x == 0)
        part[blockIdx.x] = red[0] + red[1] + red[2] + red[3];
}

// ---------------- regime softmax rows (in place) -----------------------------
__global__ __launch_bounds__(256)
void softmax_rows_r11(float* __restrict__ R)
{
    const int row = blockIdx.x;
    const int tid = threadIdx.x;
    __shared__ float  redf[256];
    __shared__ double redd[256];
    float* p = R + (long long)row * 2048;
    float mx = -1e30f;
    for (int c = tid; c < 2048; c += 256) mx = fmaxf(mx, p[c]);
    redf[tid] = mx; __syncthreads();
    for (int s2 = 128; s2; s2 >>= 1) { if (tid < s2) redf[tid] = fmaxf(redf[tid], redf[tid+s2]); __syncthreads(); }
    mx = redf[0];
    double sum = 0.0;
    for (int c = tid; c < 2048; c += 256) { float e = expf(p[c] - mx); p[c] = e; sum += e; }
    redd[tid] = sum; __syncthreads();
    for (int s2 = 128; s2; s2 >>= 1) { if (tid < s2) redd[tid] += redd[tid+s2]; __syncthreads(); }
    double tot = redd[0];
    for (int c = tid; c < 2048; c += 256) p[c] = (float)((double)p[c] / tot);
}

// ---------------- hash table per codebook entry ------------------------------
__global__ __launch_bounds__(256)
void hash_table_r11(const float* __restrict__ cb, const float* __restrict__ hw,
                    float* __restrict__ T)
{
    const int k = blockIdx.x*4 + (threadIdx.x >> 6);
    const int j = threadIdx.x & 63;
    double s = 0.0;
    for (int d = 0; d < 512; ++d)
        s += (double)cb[(long long)k*512 + d] * (double)hw[(long long)j*512 + d];
    T[(long long)k*64 + j] = (s > 0.0) ? 1.0f : 0.0f;
}

// ---------------- output writers (f32 d_out) ---------------------------------
__global__ void write_loss_r11(const double* __restrict__ part,
                               float* __restrict__ out)
{
    __shared__ double red[256];
    double s = 0.0;
    for (int i = threadIdx.x; i < 4096; i += 256) s += part[i];
    red[threadIdx.x] = s; __syncthreads();
    for (int s2 = 128; s2; s2 >>= 1) {
        if (threadIdx.x < s2) red[threadIdx.x] += red[threadIdx.x + s2];
        __syncthreads();
    }
    if (threadIdx.x == 0)
        out[O_LOSS] = (float)(1.25 * red[0] / 8388608.0);
}

__global__ __launch_bounds__(256)
void write_regime_r11(const float* __restrict__ R, const int* __restrict__ idxp,
                      float* __restrict__ out)
{
    long long i = (long long)blockIdx.x*256 + threadIdx.x;
    if (i >= 33554432LL) return;
    int n = (int)(i >> 11), c = (int)(i & 2047);
    int ci = idxp[n] & 2047;
    out[O_REG + i] = R[(long long)ci*2048 + c];
}

__global__ __launch_bounds__(256)
void write_hash_r11(const float* __restrict__ T, const int* __restrict__ idxp,
                    float* __restrict__ out)
{
    long long i = (long long)blockIdx.x*256 + threadIdx.x;
    if (i >= 1048576LL) return;
    int n = (int)(i >> 6), j = (int)(i & 63);
    int ci = idxp[n] & 2047;
    out[O_HASH + i] = T[(long long)ci*64 + j];
}

__global__ __launch_bounds__(256)
void write_idx_r11(const int* __restrict__ idxp, float* __restrict__ out)
{
    int n = blockIdx.x*256 + threadIdx.x;
    if (n >= 16384) return;
    out[O_IDX + n] = (float)(idxp[n] & 2047);
}

__global__ __launch_bounds__(256)
void write_quant_r11(const float* __restrict__ cb, const int* __restrict__ idxp,
                     float* __restrict__ out)
{
    long long i = (long long)blockIdx.x*256 + threadIdx.x;
    if (i >= 8388608LL) return;
    int n = (int)(i >> 9), d = (int)(i & 511);
    int ci = idxp[n] & 2047;
    out[O_QUANT + i] = cb[(long long)ci*512 + d];
}

// ---------------- launcher ----------------------------------------------------
extern "C" void kernel_launch(void* const* d_in, const int* in_sizes, int n_in,
                              void* d_out, int out_size, void* d_ws, size_t ws_size,
                              hipStream_t stream)
{
    (void)in_sizes; (void)n_in; (void)out_size;
    const float* market = (const float*)d_in[0];
    const float* W_in   = (const float*)d_in[1];
    const float* b_in   = (const float*)d_in[2];
    const float* pos    = (const float*)d_in[3];
    const float* c3w = (const float*)d_in[4];  const float* c3b = (const float*)d_in[5];
    const float* c5w = (const float*)d_in[6];  const float* c5b = (const float*)d_in[7];
    const float* c7w = (const float*)d_in[8];  const float* c7b = (const float*)d_in[9];
    const float* c9w = (const float*)d_in[10]; const float* c9b = (const float*)d_in[11];
    const float* msw = (const float*)d_in[12]; const float* msb = (const float*)d_in[13];
    const float* inw = (const float*)d_in[14]; const float* inb = (const float*)d_in[15];
    const float* aow = (const float*)d_in[16]; const float* aob = (const float*)d_in[17];
    const float* cb  = (const float*)d_in[18]; const float* hw  = (const float*)d_in[19];
    const float* r1w = (const float*)d_in[20]; const float* r1b = (const float*)d_in[21];
    const float* r2w = (const float*)d_in[22]; const float* r2b = (const float*)d_in[23];

    if (ws_size < (size_t)W_END * sizeof(float)) return; // insufficient scratch

    float* ws    = (float*)d_ws;
    float* xp    = ws + W_XP;
    float* convt = ws + W_CT;
    float* projp = ws + W_PROJ;
    float* wt3   = ws + W_VW;        // conv weights time-share the V region
    float* wt5   = wt3 + 512*512*3;
    float* wt7   = wt5 + 512*512*5;
    float* wt9   = wt7 + 512*512*7;
    float* Vbufp = ws + W_VW;
    float* hregp = ws + W_HREG;
    float* Tp    = ws + W_T;
    int*    idxp  = (int*)(ws + W_IDX);
    double* asump = (double*)(ws + W_ASUM);
    double* cbbp  = (double*)(ws + W_CBB);
    double* lpart = (double*)(ws + W_LPART);
    float*  pbvp  = ws + W_PBV;
    int*    pbip  = (int*)(ws + W_PBI);

    float* out = (float*)d_out;   // f32 output buffer

    float* attp  = xp;      // xp dead after conv9
    float* Kbufp = convt;   // conv_tmp dead after last ms gemm
    float* encp  = convt;   // K dead after attn
    float* Rp    = projp;   // proj dead after enc gemm

    // conv weight transposes
    conv_w_tr_r11<3><<<3072, 256, 0, stream>>>(c3w, wt3);
    conv_w_tr_r11<5><<<5120, 256, 0, stream>>>(c5w, wt5);
    conv_w_tr_r11<7><<<7168, 256, 0, stream>>>(c7w, wt7);
    conv_w_tr_r11<9><<<9216, 256, 0, stream>>>(c9w, wt9);

    const dim3 gN512(256, 8);

    // xp = market @ W_in^T + b_in + pos_enc
    gemm_bt_r11<GF_BIAS|GF_POS><<<gN512, 256, 0, stream>>>(market, W_in, b_in, pos, nullptr, xp, 512, 512, 512, 512);

    // proj = sum_c relu(conv_c(xp)) @ msW_c^T (+ bias on first)
    conv_relu_r11<3><<<gN512, 256, 0, stream>>>(xp, wt3, c3b, convt);
    gemm_bt_r11<GF_BIAS><<<gN512, 256, 0, stream>>>(convt, msw + 0*512, msb, nullptr, nullptr, projp, 512, 512, 2048, 512);
    conv_relu_r11<5><<<gN512, 256, 0, stream>>>(xp, wt5, c5b, convt);
    gemm_bt_r11<GF_ACC><<<gN512, 256, 0, stream>>>(convt, msw + 1*512, nullptr, nullptr, nullptr, projp, 512, 512, 2048, 512);
    conv_relu_r11<7><<<gN512, 256, 0, stream>>>(xp, wt7, c7b, convt);
    gemm_bt_r11<GF_ACC><<<gN512, 256, 0, stream>>>(convt, msw + 2*512, nullptr, nullptr, nullptr, projp, 512, 512, 2048, 512);
    conv_relu_r11<9><<<gN512, 256, 0, stream>>>(xp, wt9, c9b, convt);
    gemm_bt_r11<GF_ACC><<<gN512, 256, 0, stream>>>(convt, msw + 3*512, nullptr, nullptr, nullptr, projp, 512, 512, 2048, 512);

    // K, V projections (Q fused into attention). V overwrites wt (dead).
    gemm_bt_r11<GF_BIAS><<<gN512, 256, 0, stream>>>(projp, inw + 512*512,  inb + 512,  nullptr, nullptr, Kbufp, 512, 512, 512, 512);
    gemm_bt_r11<GF_BIAS><<<gN512, 256, 0, stream>>>(projp, inw + 1024*512, inb + 1024, nullptr, nullptr, Vbufp, 512, 512, 512, 512);

    attn_fused_r11<<<2048, 256, 0, stream>>>(projp, inw, inb, Kbufp, Vbufp, attp);

    // enc = proj + att @ attn_out_w^T + attn_out_b   (enc overwrites K region)
    gemm_bt_r11<GF_BIAS|GF_ADD><<<gN512, 256, 0, stream>>>(attp, aow, aob, nullptr, projp, encp, 512, 512, 512, 512);

    // VQ
    row_sumsq_r11<<<4096, 256, 0, stream>>>(encp, asump);
    row_sumsq_r11<<<512,  256, 0, stream>>>(cb, cbbp);
    vq_argmin_r11<<<dim3(256, 4), 256, 0, stream>>>(encp, cb, asump, cbbp, pbvp, pbip);
    vq_reduce_r11<<<64, 256, 0, stream>>>(pbvp, pbip, idxp);
    vq_loss_partial_r11<<<4096, 256, 0, stream>>>(encp, cb, idxp, lpart);

    // regime tables per codebook entry (R overwrites proj region, now dead)
    gemm_bt_r11<GF_BIAS|GF_RELU><<<dim3(32, 4),  256, 0, stream>>>(cb, r1w, r1b, nullptr, nullptr, hregp, 512, 512, 512, 256);
    gemm_bt_r11<GF_BIAS><<<dim3(32, 32), 256, 0, stream>>>(hregp, r2w, r2b, nullptr, nullptr, Rp, 256, 256, 256, 2048);
    softmax_rows_r11<<<2048, 256, 0, stream>>>(Rp);
    hash_table_r11<<<512, 256, 0, stream>>>(cb, hw, Tp);

    // ---- output writes (f32), every chunk fully covered each call ----
    write_loss_r11<<<1, 256, 0, stream>>>(lpart, out);
    write_regime_r11<<<131072, 256, 0, stream>>>(Rp, idxp, out);
    write_hash_r11<<<4096, 256, 0, stream>>>(Tp, idxp, out);
    write_idx_r11<<<64, 256, 0, stream>>>(idxp, out);
    write_quant_r11<<<32768, 256, 0, stream>>>(cb, idxp, out);
}